// Round 1
// baseline (915.019 us; speedup 1.0000x reference)
//
#include <hip/hip_runtime.h>
#include <math.h>

// ---------------------------------------------------------------------------
// NodeClsGAT: 3-layer GATConv (single head, PyG defaults) on MI355X.
// Strategy: build dst-CSR once per launch (ws is re-poisoned every call),
// then per layer: wave-per-row GEMM (+alpha epilogue) and wave-per-node
// softmax-aggregation with no atomics in the hot path.
// ---------------------------------------------------------------------------

#define NEG_SLOPE 0.2f

// ---------------- CSR build ----------------
__global__ void k_init_deg(int* deg, int N) {
    int i = blockIdx.x * blockDim.x + threadIdx.x;
    if (i < N) deg[i] = 1;  // self loop
}

__global__ void k_count(const int* __restrict__ dst, int E, int* deg) {
    int i = blockIdx.x * blockDim.x + threadIdx.x;
    if (i < E) atomicAdd(&deg[dst[i]], 1);
}

// block of 1024 threads scans 1024 elements (Hillis-Steele in LDS)
__global__ void k_scan1(const int* __restrict__ deg, int N, int* rowptr, int* bsums) {
    __shared__ int sm[1024];
    int gid = blockIdx.x * 1024 + threadIdx.x;
    int v = (gid < N) ? deg[gid] : 0;
    sm[threadIdx.x] = v;
    __syncthreads();
    for (int o = 1; o < 1024; o <<= 1) {
        int t = (threadIdx.x >= o) ? sm[threadIdx.x - o] : 0;
        __syncthreads();
        sm[threadIdx.x] += t;
        __syncthreads();
    }
    int incl = sm[threadIdx.x];
    if (gid < N) rowptr[gid] = incl - v;  // block-local exclusive
    if (threadIdx.x == 1023) bsums[blockIdx.x] = incl;
}

__global__ void k_scan2(int* bsums, int nb, int* rowptr, int N) {
    __shared__ int sm[1024];
    int v = (threadIdx.x < nb) ? bsums[threadIdx.x] : 0;
    sm[threadIdx.x] = v;
    __syncthreads();
    for (int o = 1; o < 1024; o <<= 1) {
        int t = (threadIdx.x >= o) ? sm[threadIdx.x - o] : 0;
        __syncthreads();
        sm[threadIdx.x] += t;
        __syncthreads();
    }
    int incl = sm[threadIdx.x];
    if (threadIdx.x < nb) bsums[threadIdx.x] = incl - v;  // exclusive block offsets
    if (threadIdx.x == nb - 1) rowptr[N] = incl;          // total = E + N
}

__global__ void k_scan3(int* rowptr, int* cursor, const int* __restrict__ bsums, int N) {
    int i = blockIdx.x * blockDim.x + threadIdx.x;
    if (i < N) {
        int v = rowptr[i] + bsums[i >> 10];
        rowptr[i] = v;
        cursor[i] = v;
    }
}

__global__ void k_scatter(const int* __restrict__ src, const int* __restrict__ dst,
                          int E, int N, int* cursor, int* csr_src) {
    int i = blockIdx.x * blockDim.x + threadIdx.x;
    if (i < E) {
        int d = dst[i];
        int pos = atomicAdd(&cursor[d], 1);
        csr_src[pos] = src[i];
    } else if (i < E + N) {
        int n = i - E;
        int pos = atomicAdd(&cursor[n], 1);
        csr_src[pos] = n;  // self loop
    }
}

// ---------------- GEMM: H = X @ W, plus alpha_src/alpha_dst epilogue -------
// wave-per-row; W (64 x FP, zero-padded) in LDS; x broadcast via shfl.
template <int FP>
__global__ __launch_bounds__(256) void k_gemm(
    const float* __restrict__ X, const float* __restrict__ W,
    const float* __restrict__ a_s, const float* __restrict__ a_d,
    int N, int Freal,
    float* __restrict__ H, float* __restrict__ asb, float* __restrict__ adb) {
    __shared__ float Wl[64 * FP];
    __shared__ float asl[FP], adl[FP];
    for (int i = threadIdx.x; i < 64 * FP; i += 256) {
        int f = i & (FP - 1);
        int k = i / FP;
        Wl[i] = (f < Freal) ? W[k * Freal + f] : 0.f;
    }
    for (int i = threadIdx.x; i < FP; i += 256) {
        asl[i] = (i < Freal) ? a_s[i] : 0.f;
        adl[i] = (i < Freal) ? a_d[i] : 0.f;
    }
    __syncthreads();

    int lane = threadIdx.x & 63;
    int lf = lane & (FP - 1);
    int wid = (blockIdx.x * blockDim.x + threadIdx.x) >> 6;
    int nw = (gridDim.x * blockDim.x) >> 6;

    for (int row = wid; row < N; row += nw) {
        float xv = X[row * 64 + lane];  // 256B coalesced
        float acc = 0.f;
#pragma unroll
        for (int k = 0; k < 64; k++) {
            float xk = __shfl(xv, k, 64);
            acc = fmaf(xk, Wl[k * FP + lf], acc);
        }
        if (lane < FP) H[row * FP + lane] = acc;  // pad lanes store 0 (W pad)
        float ps = (lane < FP) ? acc * asl[lf] : 0.f;
        float pd = (lane < FP) ? acc * adl[lf] : 0.f;
        for (int o = 32; o > 0; o >>= 1) {
            ps += __shfl_xor(ps, o, 64);
            pd += __shfl_xor(pd, o, 64);
        }
        if (lane == 0) {
            asb[row] = ps;
            adb[row] = pd;
        }
    }
}

// ---------------- Aggregation: segment softmax + weighted gather-sum -------
// One wave per dst node. mode 0: ReLU, store FP-strided. mode 1: log_softmax
// over Freal, store Freal-strided.
template <int FP>
__global__ __launch_bounds__(256) void k_agg(
    const float* __restrict__ H, const float* __restrict__ asb,
    const float* __restrict__ adb, const float* __restrict__ bias,
    const int* __restrict__ rowptr, const int* __restrict__ csr,
    int N, int Freal, float* __restrict__ out, int mode) {
    int lane = threadIdx.x & 63;
    int node = (blockIdx.x * blockDim.x + threadIdx.x) >> 6;
    if (node >= N) return;
    int start = rowptr[node];
    int end = rowptr[node + 1];
    float ad = adb[node];
    int lf = lane & (FP - 1);

    const float NEG_INF = -__builtin_inff();

    // phase 1: segment max (lanes over edges)
    float lm = NEG_INF;
    int s0 = 0;
    float e0 = NEG_INF;
    for (int base = start; base < end; base += 64) {
        int i = base + lane;
        int s = 0;
        float e = NEG_INF;
        if (i < end) {
            s = csr[i];
            float t = asb[s] + ad;
            e = (t > 0.f) ? t : NEG_SLOPE * t;
        }
        if (base == start) { s0 = s; e0 = e; }
        lm = fmaxf(lm, e);
    }
    for (int o = 32; o > 0; o >>= 1) lm = fmaxf(lm, __shfl_xor(lm, o, 64));

    // phase 2: exp-sum + weighted accumulation
    bool fast = (end - start) <= 64;
    float dsum = 0.f;
    float acc = 0.f;
    for (int base = start; base < end; base += 64) {
        int i = base + lane;
        int s;
        float e;
        if (fast) {
            s = s0;
            e = e0;
        } else {
            s = 0;
            e = NEG_INF;
            if (i < end) {
                s = csr[i];
                float t = asb[s] + ad;
                e = (t > 0.f) ? t : NEG_SLOPE * t;
            }
        }
        float p = (i < end) ? __expf(e - lm) : 0.f;
        dsum += p;
        int cnt = min(64, end - base);
        for (int j = 0; j < cnt; j++) {
            float pj = __shfl(p, j, 64);
            int sj = __shfl(s, j, 64);
            acc = fmaf(pj, H[sj * FP + lf], acc);
        }
    }
    for (int o = 32; o > 0; o >>= 1) dsum += __shfl_xor(dsum, o, 64);

    float b = (lf < Freal) ? bias[lf] : 0.f;
    float z = acc / dsum + b;

    if (mode == 0) {
        if (lane < FP) out[node * FP + lane] = fmaxf(z, 0.f);
    } else {
        float zz = (lane < Freal) ? z : NEG_INF;
        float zm = zz;
        for (int o = 32; o > 0; o >>= 1) zm = fmaxf(zm, __shfl_xor(zm, o, 64));
        float ez = (lane < Freal) ? __expf(zz - zm) : 0.f;
        float es = ez;
        for (int o = 32; o > 0; o >>= 1) es += __shfl_xor(es, o, 64);
        if (lane < Freal) out[node * Freal + lane] = zz - zm - __logf(es);
    }
}

// ---------------------------------------------------------------------------
extern "C" void kernel_launch(void* const* d_in, const int* in_sizes, int n_in,
                              void* d_out, int out_size, void* d_ws, size_t ws_size,
                              hipStream_t stream) {
    const float* x = (const float*)d_in[0];
    const int* ei = (const int*)d_in[1];
    const float* W1 = (const float*)d_in[2];
    const float* a1s = (const float*)d_in[3];
    const float* a1d = (const float*)d_in[4];
    const float* b1 = (const float*)d_in[5];
    const float* W2 = (const float*)d_in[6];
    const float* a2s = (const float*)d_in[7];
    const float* a2d = (const float*)d_in[8];
    const float* b2 = (const float*)d_in[9];
    const float* W3 = (const float*)d_in[10];
    const float* a3s = (const float*)d_in[11];
    const float* a3d = (const float*)d_in[12];
    const float* b3 = (const float*)d_in[13];

    const int N = in_sizes[0] / 64;
    const int E = in_sizes[1] / 2;
    const int Etot = E + N;
    const int* srcv = ei;
    const int* dstv = ei + E;

    // workspace carve (256B aligned)
    size_t off = 0;
    char* base = (char*)d_ws;
    auto carve = [&](size_t bytes) -> void* {
        void* p = base + off;
        off = (off + bytes + 255) & ~(size_t)255;
        return p;
    };
    int* deg = (int*)carve((size_t)N * 4);
    int* rowptr = (int*)carve((size_t)(N + 1) * 4);
    int* cursor = (int*)carve((size_t)N * 4);
    int* bsums = (int*)carve(4096);
    int* csr = (int*)carve((size_t)Etot * 4);
    float* asb = (float*)carve((size_t)N * 4);
    float* adb = (float*)carve((size_t)N * 4);
    float* bufA = (float*)carve((size_t)N * 64 * 4);
    float* bufB = (float*)carve((size_t)N * 64 * 4);
    float* bufC = (float*)carve((size_t)N * 16 * 4);

    // ---- CSR build ----
    k_init_deg<<<(N + 255) / 256, 256, 0, stream>>>(deg, N);
    k_count<<<(E + 255) / 256, 256, 0, stream>>>(dstv, E, deg);
    int nb1 = (N + 1023) / 1024;
    k_scan1<<<nb1, 1024, 0, stream>>>(deg, N, rowptr, bsums);
    k_scan2<<<1, 1024, 0, stream>>>(bsums, nb1, rowptr, N);
    k_scan3<<<(N + 255) / 256, 256, 0, stream>>>(rowptr, cursor, bsums, N);
    k_scatter<<<(Etot + 255) / 256, 256, 0, stream>>>(srcv, dstv, E, N, cursor, csr);

    const int aggBlocks = (N + 3) / 4;  // 4 waves/block, wave-per-node

    // ---- layer 1 ----
    k_gemm<64><<<2048, 256, 0, stream>>>(x, W1, a1s, a1d, N, 64, bufA, asb, adb);
    k_agg<64><<<aggBlocks, 256, 0, stream>>>(bufA, asb, adb, b1, rowptr, csr, N, 64, bufB, 0);
    // ---- layer 2 ----
    k_gemm<64><<<2048, 256, 0, stream>>>(bufB, W2, a2s, a2d, N, 64, bufA, asb, adb);
    k_agg<64><<<aggBlocks, 256, 0, stream>>>(bufA, asb, adb, b2, rowptr, csr, N, 64, bufB, 0);
    // ---- layer 3 ----
    k_gemm<16><<<2048, 256, 0, stream>>>(bufB, W3, a3s, a3d, N, 10, bufC, asb, adb);
    k_agg<16><<<aggBlocks, 256, 0, stream>>>(bufC, asb, adb, b3, rowptr, csr, N, 10,
                                             (float*)d_out, 1);
}

// Round 2
// 750.974 us; speedup vs baseline: 1.2184x; 1.2184x over previous
//
#include <hip/hip_runtime.h>
#include <math.h>

// ---------------------------------------------------------------------------
// NodeClsGAT: 3-layer GATConv (single head, PyG defaults) on MI355X.
// CSR build via 2-level bucket sort (R2): histogram dst into 512-node
// buckets, rank-scatter packed records into bucket segments (line-clustered
// writes), then per-bucket LDS count+scan emits rowptr + final csr.
// Replaces R1's atomic scatter (108 MB write-allocate thrash, 146 us).
// Layers: wave-per-row GEMM (+alpha epilogue), wave-per-node softmax-agg.
// ---------------------------------------------------------------------------

#define NEG_SLOPE 0.2f
#define BKT_BITS 9          // 512 nodes per bucket; supports N <= 262144
#define BKT_SZ   512
#define PACK_SRC_BITS 20    // src < 2^20 (N = 100000)

// ---------------- CSR build: pass A — bucket histogram ----------------
__global__ void k_zero(int* p, int n) {
    int i = blockIdx.x * blockDim.x + threadIdx.x;
    if (i < n) p[i] = 0;
}

__global__ __launch_bounds__(256) void k_hist(const int* __restrict__ dst, int E,
                                              int nb, int* __restrict__ bcount) {
    __shared__ int h[BKT_SZ];
    for (int i = threadIdx.x; i < nb; i += 256) h[i] = 0;
    __syncthreads();
    for (int i = blockIdx.x * 256 + threadIdx.x; i < E; i += gridDim.x * 256)
        atomicAdd(&h[dst[i] >> BKT_BITS], 1);
    __syncthreads();
    for (int i = threadIdx.x; i < nb; i += 256)
        if (h[i]) atomicAdd(&bcount[i], h[i]);
}

// ---------------- pass A2 — scan bucket counts (single block) ----------
__global__ __launch_bounds__(512) void k_bscan(const int* __restrict__ bcount, int nb,
                                               int E, int N, int* __restrict__ ebase,
                                               int* __restrict__ gcur,
                                               int* __restrict__ rowptr) {
    __shared__ int sm[BKT_SZ];
    int t = threadIdx.x;
    int v = (t < nb) ? bcount[t] : 0;
    sm[t] = v;
    __syncthreads();
    for (int o = 1; o < BKT_SZ; o <<= 1) {
        int tv = (t >= o) ? sm[t - o] : 0;
        __syncthreads();
        sm[t] += tv;
        __syncthreads();
    }
    int excl = sm[t] - v;
    if (t < nb) {
        ebase[t] = excl;
        gcur[t] = excl;
    }
    if (t == nb - 1) ebase[nb] = excl + v;  // == E
    if (t == 0) rowptr[N] = E + N;
}

// ---------------- pass B — rank-scatter packed records into buckets -----
// 1024 threads x 8 edges = 8192 edges per block; per-block LDS ranking so
// writes to each bucket segment are ~42 consecutive 4B records.
__global__ __launch_bounds__(1024) void k_bscatter(const int* __restrict__ src,
                                                   const int* __restrict__ dst, int E,
                                                   int nb, int* __restrict__ gcur,
                                                   int* __restrict__ ebuf) {
    __shared__ int lc[BKT_SZ];
    __shared__ int gb[BKT_SZ];
    for (int i = threadIdx.x; i < nb; i += 1024) lc[i] = 0;
    __syncthreads();
    int base = blockIdx.x * 8192;
    int bkt[8], rnk[8], pk[8];
#pragma unroll
    for (int j = 0; j < 8; j++) {
        int i = base + j * 1024 + threadIdx.x;
        bkt[j] = -1;
        if (i < E) {
            int d = dst[i];
            int s = src[i];
            int b = d >> BKT_BITS;
            bkt[j] = b;
            rnk[j] = atomicAdd(&lc[b], 1);
            pk[j] = ((d & (BKT_SZ - 1)) << PACK_SRC_BITS) | s;
        }
    }
    __syncthreads();
    for (int b = threadIdx.x; b < nb; b += 1024)
        if (lc[b]) gb[b] = atomicAdd(&gcur[b], lc[b]);
    __syncthreads();
#pragma unroll
    for (int j = 0; j < 8; j++)
        if (bkt[j] >= 0) ebuf[gb[bkt[j]] + rnk[j]] = pk[j];
}

// ---------------- pass C — per-bucket CSR finalize ----------------------
// Block b owns nodes [b*512, b*512+512). Count per-node in LDS, scan
// (cnt+1 self-loop), write rowptr, self-loops, and bucket-local csr.
__global__ __launch_bounds__(512) void k_bcsr(const int* __restrict__ ebuf,
                                              const int* __restrict__ ebase, int N,
                                              int* __restrict__ rowptr,
                                              int* __restrict__ csr) {
    __shared__ int cnt[BKT_SZ];
    __shared__ int sm[BKT_SZ];
    int b = blockIdx.x;
    int t = threadIdx.x;
    int n0 = b << BKT_BITS;
    int nn = min(BKT_SZ, N - n0);
    cnt[t] = 0;
    __syncthreads();
    int e0 = ebase[b], e1 = ebase[b + 1];
    for (int i = e0 + t; i < e1; i += BKT_SZ)
        atomicAdd(&cnt[ebuf[i] >> PACK_SRC_BITS], 1);
    __syncthreads();
    int v = cnt[t] + (t < nn ? 1 : 0);  // +1 self-loop slot per valid node
    sm[t] = v;
    __syncthreads();
    for (int o = 1; o < BKT_SZ; o <<= 1) {
        int tv = (t >= o) ? sm[t - o] : 0;
        __syncthreads();
        sm[t] += tv;
        __syncthreads();
    }
    int excl = sm[t] - v;
    int cb = e0 + n0;  // csr base for this bucket: edges before + self-loops before
    if (t < nn) {
        rowptr[n0 + t] = cb + excl;
        csr[cb + excl] = n0 + t;  // self-loop at slot 0 of the node's segment
    }
    cnt[t] = excl + 1;  // edge cursor (after self-loop)
    __syncthreads();
    for (int i = e0 + t; i < e1; i += BKT_SZ) {
        int p = ebuf[i];
        int dl = p >> PACK_SRC_BITS;
        int pos = atomicAdd(&cnt[dl], 1);
        csr[cb + pos] = p & ((1 << PACK_SRC_BITS) - 1);
    }
}

// ---------------- GEMM: H = X @ W, plus alpha_src/alpha_dst epilogue -------
// wave-per-row; W (64 x FP, zero-padded) in LDS; x broadcast via shfl.
template <int FP>
__global__ __launch_bounds__(256) void k_gemm(
    const float* __restrict__ X, const float* __restrict__ W,
    const float* __restrict__ a_s, const float* __restrict__ a_d,
    int N, int Freal,
    float* __restrict__ H, float* __restrict__ asb, float* __restrict__ adb) {
    __shared__ float Wl[64 * FP];
    __shared__ float asl[FP], adl[FP];
    for (int i = threadIdx.x; i < 64 * FP; i += 256) {
        int f = i & (FP - 1);
        int k = i / FP;
        Wl[i] = (f < Freal) ? W[k * Freal + f] : 0.f;
    }
    for (int i = threadIdx.x; i < FP; i += 256) {
        asl[i] = (i < Freal) ? a_s[i] : 0.f;
        adl[i] = (i < Freal) ? a_d[i] : 0.f;
    }
    __syncthreads();

    int lane = threadIdx.x & 63;
    int lf = lane & (FP - 1);
    int wid = (blockIdx.x * blockDim.x + threadIdx.x) >> 6;
    int nw = (gridDim.x * blockDim.x) >> 6;

    for (int row = wid; row < N; row += nw) {
        float xv = X[row * 64 + lane];  // 256B coalesced
        float acc = 0.f;
#pragma unroll
        for (int k = 0; k < 64; k++) {
            float xk = __shfl(xv, k, 64);
            acc = fmaf(xk, Wl[k * FP + lf], acc);
        }
        if (lane < FP) H[row * FP + lane] = acc;  // pad lanes store 0 (W pad)
        float ps = (lane < FP) ? acc * asl[lf] : 0.f;
        float pd = (lane < FP) ? acc * adl[lf] : 0.f;
        for (int o = 32; o > 0; o >>= 1) {
            ps += __shfl_xor(ps, o, 64);
            pd += __shfl_xor(pd, o, 64);
        }
        if (lane == 0) {
            asb[row] = ps;
            adb[row] = pd;
        }
    }
}

// ---------------- Aggregation: segment softmax + weighted gather-sum -------
// One wave per dst node. mode 0: ReLU, store FP-strided. mode 1: log_softmax
// over Freal, store Freal-strided.
template <int FP>
__global__ __launch_bounds__(256) void k_agg(
    const float* __restrict__ H, const float* __restrict__ asb,
    const float* __restrict__ adb, const float* __restrict__ bias,
    const int* __restrict__ rowptr, const int* __restrict__ csr,
    int N, int Freal, float* __restrict__ out, int mode) {
    int lane = threadIdx.x & 63;
    int node = (blockIdx.x * blockDim.x + threadIdx.x) >> 6;
    if (node >= N) return;
    int start = rowptr[node];
    int end = rowptr[node + 1];
    float ad = adb[node];
    int lf = lane & (FP - 1);

    const float NEG_INF = -__builtin_inff();

    // phase 1: segment max (lanes over edges)
    float lm = NEG_INF;
    int s0 = 0;
    float e0 = NEG_INF;
    for (int base = start; base < end; base += 64) {
        int i = base + lane;
        int s = 0;
        float e = NEG_INF;
        if (i < end) {
            s = csr[i];
            float t = asb[s] + ad;
            e = (t > 0.f) ? t : NEG_SLOPE * t;
        }
        if (base == start) { s0 = s; e0 = e; }
        lm = fmaxf(lm, e);
    }
    for (int o = 32; o > 0; o >>= 1) lm = fmaxf(lm, __shfl_xor(lm, o, 64));

    // phase 2: exp-sum + weighted accumulation
    bool fast = (end - start) <= 64;
    float dsum = 0.f;
    float acc = 0.f;
    for (int base = start; base < end; base += 64) {
        int i = base + lane;
        int s;
        float e;
        if (fast) {
            s = s0;
            e = e0;
        } else {
            s = 0;
            e = NEG_INF;
            if (i < end) {
                s = csr[i];
                float t = asb[s] + ad;
                e = (t > 0.f) ? t : NEG_SLOPE * t;
            }
        }
        float p = (i < end) ? __expf(e - lm) : 0.f;
        dsum += p;
        int cnt = min(64, end - base);
        for (int j = 0; j < cnt; j++) {
            float pj = __shfl(p, j, 64);
            int sj = __shfl(s, j, 64);
            acc = fmaf(pj, H[sj * FP + lf], acc);
        }
    }
    for (int o = 32; o > 0; o >>= 1) dsum += __shfl_xor(dsum, o, 64);

    float b = (lf < Freal) ? bias[lf] : 0.f;
    float z = acc / dsum + b;

    if (mode == 0) {
        if (lane < FP) out[node * FP + lane] = fmaxf(z, 0.f);
    } else {
        float zz = (lane < Freal) ? z : NEG_INF;
        float zm = zz;
        for (int o = 32; o > 0; o >>= 1) zm = fmaxf(zm, __shfl_xor(zm, o, 64));
        float ez = (lane < Freal) ? __expf(zz - zm) : 0.f;
        float es = ez;
        for (int o = 32; o > 0; o >>= 1) es += __shfl_xor(es, o, 64);
        if (lane < Freal) out[node * Freal + lane] = zz - zm - __logf(es);
    }
}

// ---------------------------------------------------------------------------
extern "C" void kernel_launch(void* const* d_in, const int* in_sizes, int n_in,
                              void* d_out, int out_size, void* d_ws, size_t ws_size,
                              hipStream_t stream) {
    const float* x = (const float*)d_in[0];
    const int* ei = (const int*)d_in[1];
    const float* W1 = (const float*)d_in[2];
    const float* a1s = (const float*)d_in[3];
    const float* a1d = (const float*)d_in[4];
    const float* b1 = (const float*)d_in[5];
    const float* W2 = (const float*)d_in[6];
    const float* a2s = (const float*)d_in[7];
    const float* a2d = (const float*)d_in[8];
    const float* b2 = (const float*)d_in[9];
    const float* W3 = (const float*)d_in[10];
    const float* a3s = (const float*)d_in[11];
    const float* a3d = (const float*)d_in[12];
    const float* b3 = (const float*)d_in[13];

    const int N = in_sizes[0] / 64;
    const int E = in_sizes[1] / 2;
    const int Etot = E + N;
    const int nb = (N + BKT_SZ - 1) >> BKT_BITS;  // buckets of 512 nodes
    const int* srcv = ei;
    const int* dstv = ei + E;

    // workspace carve (256B aligned)
    size_t off = 0;
    char* base = (char*)d_ws;
    auto carve = [&](size_t bytes) -> void* {
        void* p = base + off;
        off = (off + bytes + 255) & ~(size_t)255;
        return p;
    };
    int* bcount = (int*)carve((size_t)(nb + 1) * 4);
    int* ebase = (int*)carve((size_t)(nb + 1) * 4);
    int* gcur = (int*)carve((size_t)nb * 4);
    int* rowptr = (int*)carve((size_t)(N + 1) * 4);
    int* csr = (int*)carve((size_t)Etot * 4);
    float* asb = (float*)carve((size_t)N * 4);
    float* adb = (float*)carve((size_t)N * 4);
    float* bufA = (float*)carve((size_t)N * 64 * 4);
    float* bufB = (float*)carve((size_t)N * 64 * 4);
    float* bufC = (float*)carve((size_t)N * 16 * 4);
    int* ebuf = (int*)bufA;  // alias: ebuf only live before layer-1 GEMM

    // ---- CSR build (bucket sort) ----
    k_zero<<<(nb + 255) / 256, 256, 0, stream>>>(bcount, nb);
    k_hist<<<512, 256, 0, stream>>>(dstv, E, nb, bcount);
    k_bscan<<<1, BKT_SZ, 0, stream>>>(bcount, nb, E, N, ebase, gcur, rowptr);
    k_bscatter<<<(E + 8191) / 8192, 1024, 0, stream>>>(srcv, dstv, E, nb, gcur, ebuf);
    k_bcsr<<<nb, BKT_SZ, 0, stream>>>(ebuf, ebase, N, rowptr, csr);

    const int aggBlocks = (N + 3) / 4;  // 4 waves/block, wave-per-node

    // ---- layer 1 ----
    k_gemm<64><<<2048, 256, 0, stream>>>(x, W1, a1s, a1d, N, 64, bufA, asb, adb);
    k_agg<64><<<aggBlocks, 256, 0, stream>>>(bufA, asb, adb, b1, rowptr, csr, N, 64, bufB, 0);
    // ---- layer 2 ----
    k_gemm<64><<<2048, 256, 0, stream>>>(bufB, W2, a2s, a2d, N, 64, bufA, asb, adb);
    k_agg<64><<<aggBlocks, 256, 0, stream>>>(bufA, asb, adb, b2, rowptr, csr, N, 64, bufB, 0);
    // ---- layer 3 ----
    k_gemm<16><<<2048, 256, 0, stream>>>(bufB, W3, a3s, a3d, N, 10, bufC, asb, adb);
    k_agg<16><<<aggBlocks, 256, 0, stream>>>(bufC, asb, adb, b3, rowptr, csr, N, 10,
                                             (float*)d_out, 1);
}

// Round 4
// 617.260 us; speedup vs baseline: 1.4824x; 1.2166x over previous
//
#include <hip/hip_runtime.h>
#include <math.h>

// ---------------------------------------------------------------------------
// NodeClsGAT: 3-layer GATConv (single head, PyG defaults) on MI355X.
// CSR build via 2-level bucket sort (R2). R4: k_agg = R2's proven structure
// with the edge loop unroll-jammed by 4 (4 gather loads in flight). R3's
// lane-group/float4 restructure FAILED correctness (divergent-trip-count
// loop with convergent shfl — reverted; all shfl loops here have
// wave-uniform bounds).
// ---------------------------------------------------------------------------

#define NEG_SLOPE 0.2f
#define BKT_BITS 9          // 512 nodes per bucket; supports N <= 262144
#define BKT_SZ   512
#define PACK_SRC_BITS 20    // src < 2^20 (N = 100000)

// ---------------- CSR build: pass A — bucket histogram ----------------
__global__ void k_zero(int* p, int n) {
    int i = blockIdx.x * blockDim.x + threadIdx.x;
    if (i < n) p[i] = 0;
}

__global__ __launch_bounds__(256) void k_hist(const int* __restrict__ dst, int E,
                                              int nb, int* __restrict__ bcount) {
    __shared__ int h[BKT_SZ];
    for (int i = threadIdx.x; i < nb; i += 256) h[i] = 0;
    __syncthreads();
    for (int i = blockIdx.x * 256 + threadIdx.x; i < E; i += gridDim.x * 256)
        atomicAdd(&h[dst[i] >> BKT_BITS], 1);
    __syncthreads();
    for (int i = threadIdx.x; i < nb; i += 256)
        if (h[i]) atomicAdd(&bcount[i], h[i]);
}

// ---------------- pass A2 — scan bucket counts (single block) ----------
__global__ __launch_bounds__(512) void k_bscan(const int* __restrict__ bcount, int nb,
                                               int E, int N, int* __restrict__ ebase,
                                               int* __restrict__ gcur,
                                               int* __restrict__ rowptr) {
    __shared__ int sm[BKT_SZ];
    int t = threadIdx.x;
    int v = (t < nb) ? bcount[t] : 0;
    sm[t] = v;
    __syncthreads();
    for (int o = 1; o < BKT_SZ; o <<= 1) {
        int tv = (t >= o) ? sm[t - o] : 0;
        __syncthreads();
        sm[t] += tv;
        __syncthreads();
    }
    int excl = sm[t] - v;
    if (t < nb) {
        ebase[t] = excl;
        gcur[t] = excl;
    }
    if (t == nb - 1) ebase[nb] = excl + v;  // == E
    if (t == 0) rowptr[N] = E + N;
}

// ---------------- pass B — rank-scatter packed records into buckets -----
__global__ __launch_bounds__(1024) void k_bscatter(const int* __restrict__ src,
                                                   const int* __restrict__ dst, int E,
                                                   int nb, int* __restrict__ gcur,
                                                   int* __restrict__ ebuf) {
    __shared__ int lc[BKT_SZ];
    __shared__ int gb[BKT_SZ];
    for (int i = threadIdx.x; i < nb; i += 1024) lc[i] = 0;
    __syncthreads();
    int base = blockIdx.x * 8192;
    int bkt[8], rnk[8], pk[8];
#pragma unroll
    for (int j = 0; j < 8; j++) {
        int i = base + j * 1024 + threadIdx.x;
        bkt[j] = -1;
        if (i < E) {
            int d = dst[i];
            int s = src[i];
            int b = d >> BKT_BITS;
            bkt[j] = b;
            rnk[j] = atomicAdd(&lc[b], 1);
            pk[j] = ((d & (BKT_SZ - 1)) << PACK_SRC_BITS) | s;
        }
    }
    __syncthreads();
    for (int b = threadIdx.x; b < nb; b += 1024)
        if (lc[b]) gb[b] = atomicAdd(&gcur[b], lc[b]);
    __syncthreads();
#pragma unroll
    for (int j = 0; j < 8; j++)
        if (bkt[j] >= 0) ebuf[gb[bkt[j]] + rnk[j]] = pk[j];
}

// ---------------- pass C — per-bucket CSR finalize ----------------------
__global__ __launch_bounds__(512) void k_bcsr(const int* __restrict__ ebuf,
                                              const int* __restrict__ ebase, int N,
                                              int* __restrict__ rowptr,
                                              int* __restrict__ csr) {
    __shared__ int cnt[BKT_SZ];
    __shared__ int sm[BKT_SZ];
    int b = blockIdx.x;
    int t = threadIdx.x;
    int n0 = b << BKT_BITS;
    int nn = min(BKT_SZ, N - n0);
    cnt[t] = 0;
    __syncthreads();
    int e0 = ebase[b], e1 = ebase[b + 1];
    for (int i = e0 + t; i < e1; i += BKT_SZ)
        atomicAdd(&cnt[ebuf[i] >> PACK_SRC_BITS], 1);
    __syncthreads();
    int v = cnt[t] + (t < nn ? 1 : 0);  // +1 self-loop slot per valid node
    sm[t] = v;
    __syncthreads();
    for (int o = 1; o < BKT_SZ; o <<= 1) {
        int tv = (t >= o) ? sm[t - o] : 0;
        __syncthreads();
        sm[t] += tv;
        __syncthreads();
    }
    int excl = sm[t] - v;
    int cb = e0 + n0;  // csr base: edges before bucket + self-loops before bucket
    if (t < nn) {
        rowptr[n0 + t] = cb + excl;
        csr[cb + excl] = n0 + t;  // self-loop at slot 0 of the node's segment
    }
    cnt[t] = excl + 1;  // edge cursor (after self-loop)
    __syncthreads();
    for (int i = e0 + t; i < e1; i += BKT_SZ) {
        int p = ebuf[i];
        int dl = p >> PACK_SRC_BITS;
        int pos = atomicAdd(&cnt[dl], 1);
        csr[cb + pos] = p & ((1 << PACK_SRC_BITS) - 1);
    }
}

// ---------------- GEMM: H = X @ W, plus alpha_src/alpha_dst epilogue -------
template <int FP>
__global__ __launch_bounds__(256) void k_gemm(
    const float* __restrict__ X, const float* __restrict__ W,
    const float* __restrict__ a_s, const float* __restrict__ a_d,
    int N, int Freal,
    float* __restrict__ H, float* __restrict__ asb, float* __restrict__ adb) {
    __shared__ float Wl[64 * FP];
    __shared__ float asl[FP], adl[FP];
    for (int i = threadIdx.x; i < 64 * FP; i += 256) {
        int f = i & (FP - 1);
        int k = i / FP;
        Wl[i] = (f < Freal) ? W[k * Freal + f] : 0.f;
    }
    for (int i = threadIdx.x; i < FP; i += 256) {
        asl[i] = (i < Freal) ? a_s[i] : 0.f;
        adl[i] = (i < Freal) ? a_d[i] : 0.f;
    }
    __syncthreads();

    int lane = threadIdx.x & 63;
    int lf = lane & (FP - 1);
    int wid = (blockIdx.x * blockDim.x + threadIdx.x) >> 6;
    int nw = (gridDim.x * blockDim.x) >> 6;

    for (int row = wid; row < N; row += nw) {
        float xv = X[row * 64 + lane];  // 256B coalesced
        float acc = 0.f;
#pragma unroll
        for (int k = 0; k < 64; k++) {
            float xk = __shfl(xv, k, 64);
            acc = fmaf(xk, Wl[k * FP + lf], acc);
        }
        if (lane < FP) H[row * FP + lane] = acc;  // pad lanes store 0 (W pad)
        float ps = (lane < FP) ? acc * asl[lf] : 0.f;
        float pd = (lane < FP) ? acc * adl[lf] : 0.f;
        for (int o = 32; o > 0; o >>= 1) {
            ps += __shfl_xor(ps, o, 64);
            pd += __shfl_xor(pd, o, 64);
        }
        if (lane == 0) {
            asb[row] = ps;
            adb[row] = pd;
        }
    }
}

// ---------------- Aggregation: segment softmax + weighted gather-sum -------
// One wave per dst node; lane covers feature lf (R2's proven layout). Edge
// loop unroll-jammed by 4: batch shuffles, 4 independent gathers in flight.
// All shfl loops have wave-uniform trip counts. mode 0: ReLU, stride FP.
// mode 1: log_softmax over Freal, stride Freal.
template <int FP>
__global__ __launch_bounds__(256) void k_agg(
    const float* __restrict__ H, const float* __restrict__ asb,
    const float* __restrict__ adb, const float* __restrict__ bias,
    const int* __restrict__ rowptr, const int* __restrict__ csr,
    int N, int Freal, float* __restrict__ out, int mode) {
    int lane = threadIdx.x & 63;
    int node = (blockIdx.x * blockDim.x + threadIdx.x) >> 6;
    if (node >= N) return;
    int start = rowptr[node];
    int end = rowptr[node + 1];
    int deg = end - start;
    float ad = adb[node];
    int lf = lane & (FP - 1);

    const float NEG_INF = -__builtin_inff();
    float acc = 0.f;
    float dsum = 0.f;

    if (deg <= 64) {
        // fast path: scores fully in registers
        int s = 0;
        float e = NEG_INF;
        if (lane < deg) {
            s = csr[start + lane];
            float t = asb[s] + ad;
            e = (t > 0.f) ? t : NEG_SLOPE * t;
        }
        float m = e;
        for (int o = 32; o > 0; o >>= 1) m = fmaxf(m, __shfl_xor(m, o, 64));
        float p = (lane < deg) ? __expf(e - m) : 0.f;
        dsum = p;
        int j = 0;
        for (; j + 4 <= deg; j += 4) {
            float p0 = __shfl(p, j, 64), p1 = __shfl(p, j + 1, 64);
            float p2 = __shfl(p, j + 2, 64), p3 = __shfl(p, j + 3, 64);
            int q0 = __shfl(s, j, 64), q1 = __shfl(s, j + 1, 64);
            int q2 = __shfl(s, j + 2, 64), q3 = __shfl(s, j + 3, 64);
            float r0 = H[(size_t)q0 * FP + lf];
            float r1 = H[(size_t)q1 * FP + lf];
            float r2 = H[(size_t)q2 * FP + lf];
            float r3 = H[(size_t)q3 * FP + lf];
            acc = fmaf(p0, r0, acc);
            acc = fmaf(p1, r1, acc);
            acc = fmaf(p2, r2, acc);
            acc = fmaf(p3, r3, acc);
        }
        for (; j < deg; j++) {
            float pj = __shfl(p, j, 64);
            int sj = __shfl(s, j, 64);
            acc = fmaf(pj, H[(size_t)sj * FP + lf], acc);
        }
    } else {
        // slow path (deg > 64, essentially never at mean deg ~17): two-pass
        float m = NEG_INF;
        for (int base = start; base < end; base += 64) {
            int i = base + lane;
            if (i < end) {
                float t = asb[csr[i]] + ad;
                float e = (t > 0.f) ? t : NEG_SLOPE * t;
                m = fmaxf(m, e);
            }
        }
        for (int o = 32; o > 0; o >>= 1) m = fmaxf(m, __shfl_xor(m, o, 64));
        for (int base = start; base < end; base += 64) {
            int i = base + lane;
            int cnt = min(64, end - base);
            int s = 0;
            float p = 0.f;
            if (i < end) {
                s = csr[i];
                float t = asb[s] + ad;
                float e = (t > 0.f) ? t : NEG_SLOPE * t;
                p = __expf(e - m);
            }
            dsum += p;
            int j = 0;
            for (; j + 4 <= cnt; j += 4) {
                float p0 = __shfl(p, j, 64), p1 = __shfl(p, j + 1, 64);
                float p2 = __shfl(p, j + 2, 64), p3 = __shfl(p, j + 3, 64);
                int q0 = __shfl(s, j, 64), q1 = __shfl(s, j + 1, 64);
                int q2 = __shfl(s, j + 2, 64), q3 = __shfl(s, j + 3, 64);
                float r0 = H[(size_t)q0 * FP + lf];
                float r1 = H[(size_t)q1 * FP + lf];
                float r2 = H[(size_t)q2 * FP + lf];
                float r3 = H[(size_t)q3 * FP + lf];
                acc = fmaf(p0, r0, acc);
                acc = fmaf(p1, r1, acc);
                acc = fmaf(p2, r2, acc);
                acc = fmaf(p3, r3, acc);
            }
            for (; j < cnt; j++) {
                float pj = __shfl(p, j, 64);
                int sj = __shfl(s, j, 64);
                acc = fmaf(pj, H[(size_t)sj * FP + lf], acc);
            }
        }
    }
    for (int o = 32; o > 0; o >>= 1) dsum += __shfl_xor(dsum, o, 64);

    float b = (lf < Freal) ? bias[lf] : 0.f;
    float z = acc / dsum + b;

    if (mode == 0) {
        if (lane < FP) out[(size_t)node * FP + lane] = fmaxf(z, 0.f);
    } else {
        float zz = (lane < Freal) ? z : NEG_INF;
        float zm = zz;
        for (int o = 32; o > 0; o >>= 1) zm = fmaxf(zm, __shfl_xor(zm, o, 64));
        float ez = (lane < Freal) ? __expf(zz - zm) : 0.f;
        float es = ez;
        for (int o = 32; o > 0; o >>= 1) es += __shfl_xor(es, o, 64);
        if (lane < Freal) out[(size_t)node * Freal + lane] = zz - zm - __logf(es);
    }
}

// ---------------------------------------------------------------------------
extern "C" void kernel_launch(void* const* d_in, const int* in_sizes, int n_in,
                              void* d_out, int out_size, void* d_ws, size_t ws_size,
                              hipStream_t stream) {
    const float* x = (const float*)d_in[0];
    const int* ei = (const int*)d_in[1];
    const float* W1 = (const float*)d_in[2];
    const float* a1s = (const float*)d_in[3];
    const float* a1d = (const float*)d_in[4];
    const float* b1 = (const float*)d_in[5];
    const float* W2 = (const float*)d_in[6];
    const float* a2s = (const float*)d_in[7];
    const float* a2d = (const float*)d_in[8];
    const float* b2 = (const float*)d_in[9];
    const float* W3 = (const float*)d_in[10];
    const float* a3s = (const float*)d_in[11];
    const float* a3d = (const float*)d_in[12];
    const float* b3 = (const float*)d_in[13];

    const int N = in_sizes[0] / 64;
    const int E = in_sizes[1] / 2;
    const int Etot = E + N;
    const int nb = (N + BKT_SZ - 1) >> BKT_BITS;  // buckets of 512 nodes
    const int* srcv = ei;
    const int* dstv = ei + E;

    // workspace carve (256B aligned)
    size_t off = 0;
    char* base = (char*)d_ws;
    auto carve = [&](size_t bytes) -> void* {
        void* p = base + off;
        off = (off + bytes + 255) & ~(size_t)255;
        return p;
    };
    int* bcount = (int*)carve((size_t)(nb + 1) * 4);
    int* ebase = (int*)carve((size_t)(nb + 1) * 4);
    int* gcur = (int*)carve((size_t)nb * 4);
    int* rowptr = (int*)carve((size_t)(N + 1) * 4);
    int* csr = (int*)carve((size_t)Etot * 4);
    float* asb = (float*)carve((size_t)N * 4);
    float* adb = (float*)carve((size_t)N * 4);
    float* bufA = (float*)carve((size_t)N * 64 * 4);
    float* bufB = (float*)carve((size_t)N * 64 * 4);
    float* bufC = (float*)carve((size_t)N * 16 * 4);
    int* ebuf = (int*)bufA;  // alias: ebuf only live before layer-1 GEMM

    // ---- CSR build (bucket sort) ----
    k_zero<<<(nb + 255) / 256, 256, 0, stream>>>(bcount, nb);
    k_hist<<<512, 256, 0, stream>>>(dstv, E, nb, bcount);
    k_bscan<<<1, BKT_SZ, 0, stream>>>(bcount, nb, E, N, ebase, gcur, rowptr);
    k_bscatter<<<(E + 8191) / 8192, 1024, 0, stream>>>(srcv, dstv, E, nb, gcur, ebuf);
    k_bcsr<<<nb, BKT_SZ, 0, stream>>>(ebuf, ebase, N, rowptr, csr);

    const int aggBlocks = (N + 3) / 4;  // 4 waves/block, wave-per-node

    // ---- layer 1 ----
    k_gemm<64><<<2048, 256, 0, stream>>>(x, W1, a1s, a1d, N, 64, bufA, asb, adb);
    k_agg<64><<<aggBlocks, 256, 0, stream>>>(bufA, asb, adb, b1, rowptr, csr, N, 64, bufB, 0);
    // ---- layer 2 ----
    k_gemm<64><<<2048, 256, 0, stream>>>(bufB, W2, a2s, a2d, N, 64, bufA, asb, adb);
    k_agg<64><<<aggBlocks, 256, 0, stream>>>(bufA, asb, adb, b2, rowptr, csr, N, 64, bufB, 0);
    // ---- layer 3 ----
    k_gemm<16><<<2048, 256, 0, stream>>>(bufB, W3, a3s, a3d, N, 10, bufC, asb, adb);
    k_agg<16><<<aggBlocks, 256, 0, stream>>>(bufC, asb, adb, b3, rowptr, csr, N, 10,
                                             (float*)d_out, 1);
}

// Round 5
// 451.189 us; speedup vs baseline: 2.0280x; 1.3681x over previous
//
#include <hip/hip_runtime.h>
#include <math.h>

// ---------------------------------------------------------------------------
// NodeClsGAT: 3-layer GATConv (single head, PyG defaults) on MI355X.
// CSR build via 2-level bucket sort (R2). k_agg: R4's unroll-by-4 gather.
// R5: k_gemm rewritten — W column held in 64 VGPRs per lane, x row read via
// wave-uniform scalar loads (readfirstlane + const __restrict__ promotes to
// s_load_dwordx16). R4's GEMM was LDS-pipe-bound (64 shfl + 64 ds_read per
// row = 755 cyc/row = 100us); new inner loop is 64 v_fma, zero LDS ops.
// ---------------------------------------------------------------------------

#define NEG_SLOPE 0.2f
#define BKT_BITS 9          // 512 nodes per bucket; supports N <= 262144
#define BKT_SZ   512
#define PACK_SRC_BITS 20    // src < 2^20 (N = 100000)

// ---------------- CSR build: pass A — bucket histogram ----------------
__global__ void k_zero(int* p, int n) {
    int i = blockIdx.x * blockDim.x + threadIdx.x;
    if (i < n) p[i] = 0;
}

__global__ __launch_bounds__(256) void k_hist(const int* __restrict__ dst, int E,
                                              int nb, int* __restrict__ bcount) {
    __shared__ int h[BKT_SZ];
    for (int i = threadIdx.x; i < nb; i += 256) h[i] = 0;
    __syncthreads();
    for (int i = blockIdx.x * 256 + threadIdx.x; i < E; i += gridDim.x * 256)
        atomicAdd(&h[dst[i] >> BKT_BITS], 1);
    __syncthreads();
    for (int i = threadIdx.x; i < nb; i += 256)
        if (h[i]) atomicAdd(&bcount[i], h[i]);
}

// ---------------- pass A2 — scan bucket counts (single block) ----------
__global__ __launch_bounds__(512) void k_bscan(const int* __restrict__ bcount, int nb,
                                               int E, int N, int* __restrict__ ebase,
                                               int* __restrict__ gcur,
                                               int* __restrict__ rowptr) {
    __shared__ int sm[BKT_SZ];
    int t = threadIdx.x;
    int v = (t < nb) ? bcount[t] : 0;
    sm[t] = v;
    __syncthreads();
    for (int o = 1; o < BKT_SZ; o <<= 1) {
        int tv = (t >= o) ? sm[t - o] : 0;
        __syncthreads();
        sm[t] += tv;
        __syncthreads();
    }
    int excl = sm[t] - v;
    if (t < nb) {
        ebase[t] = excl;
        gcur[t] = excl;
    }
    if (t == nb - 1) ebase[nb] = excl + v;  // == E
    if (t == 0) rowptr[N] = E + N;
}

// ---------------- pass B — rank-scatter packed records into buckets -----
__global__ __launch_bounds__(1024) void k_bscatter(const int* __restrict__ src,
                                                   const int* __restrict__ dst, int E,
                                                   int nb, int* __restrict__ gcur,
                                                   int* __restrict__ ebuf) {
    __shared__ int lc[BKT_SZ];
    __shared__ int gb[BKT_SZ];
    for (int i = threadIdx.x; i < nb; i += 1024) lc[i] = 0;
    __syncthreads();
    int base = blockIdx.x * 8192;
    int bkt[8], rnk[8], pk[8];
#pragma unroll
    for (int j = 0; j < 8; j++) {
        int i = base + j * 1024 + threadIdx.x;
        bkt[j] = -1;
        if (i < E) {
            int d = dst[i];
            int s = src[i];
            int b = d >> BKT_BITS;
            bkt[j] = b;
            rnk[j] = atomicAdd(&lc[b], 1);
            pk[j] = ((d & (BKT_SZ - 1)) << PACK_SRC_BITS) | s;
        }
    }
    __syncthreads();
    for (int b = threadIdx.x; b < nb; b += 1024)
        if (lc[b]) gb[b] = atomicAdd(&gcur[b], lc[b]);
    __syncthreads();
#pragma unroll
    for (int j = 0; j < 8; j++)
        if (bkt[j] >= 0) ebuf[gb[bkt[j]] + rnk[j]] = pk[j];
}

// ---------------- pass C — per-bucket CSR finalize ----------------------
__global__ __launch_bounds__(512) void k_bcsr(const int* __restrict__ ebuf,
                                              const int* __restrict__ ebase, int N,
                                              int* __restrict__ rowptr,
                                              int* __restrict__ csr) {
    __shared__ int cnt[BKT_SZ];
    __shared__ int sm[BKT_SZ];
    int b = blockIdx.x;
    int t = threadIdx.x;
    int n0 = b << BKT_BITS;
    int nn = min(BKT_SZ, N - n0);
    cnt[t] = 0;
    __syncthreads();
    int e0 = ebase[b], e1 = ebase[b + 1];
    for (int i = e0 + t; i < e1; i += BKT_SZ)
        atomicAdd(&cnt[ebuf[i] >> PACK_SRC_BITS], 1);
    __syncthreads();
    int v = cnt[t] + (t < nn ? 1 : 0);  // +1 self-loop slot per valid node
    sm[t] = v;
    __syncthreads();
    for (int o = 1; o < BKT_SZ; o <<= 1) {
        int tv = (t >= o) ? sm[t - o] : 0;
        __syncthreads();
        sm[t] += tv;
        __syncthreads();
    }
    int excl = sm[t] - v;
    int cb = e0 + n0;  // csr base: edges before bucket + self-loops before bucket
    if (t < nn) {
        rowptr[n0 + t] = cb + excl;
        csr[cb + excl] = n0 + t;  // self-loop at slot 0 of the node's segment
    }
    cnt[t] = excl + 1;  // edge cursor (after self-loop)
    __syncthreads();
    for (int i = e0 + t; i < e1; i += BKT_SZ) {
        int p = ebuf[i];
        int dl = p >> PACK_SRC_BITS;
        int pos = atomicAdd(&cnt[dl], 1);
        csr[cb + pos] = p & ((1 << PACK_SRC_BITS) - 1);
    }
}

// ---------------- GEMM: H = X @ W, plus alpha_src/alpha_dst epilogue -------
// R5: wave-per-row; lane holds W[:,lf] in 64 VGPRs; x row read via
// wave-uniform scalar loads; inner loop = 64 v_fma (no LDS ops).
template <int FP>
__global__ __launch_bounds__(256) void k_gemm(
    const float* __restrict__ X, const float* __restrict__ W,
    const float* __restrict__ a_s, const float* __restrict__ a_d,
    int N, int Freal,
    float* __restrict__ H, float* __restrict__ asb, float* __restrict__ adb) {
    int lane = threadIdx.x & 63;
    int lf = lane & (FP - 1);

    float w[64];
#pragma unroll
    for (int k = 0; k < 64; k++)
        w[k] = (lf < Freal) ? W[k * Freal + lf] : 0.f;
    float av = (lf < Freal) ? a_s[lf] : 0.f;
    float dv = (lf < Freal) ? a_d[lf] : 0.f;

    int wid = (blockIdx.x * blockDim.x + threadIdx.x) >> 6;
    int nw = (gridDim.x * blockDim.x) >> 6;

    for (int row = wid; row < N; row += nw) {
        // wave-uniform pointer -> compiler promotes to s_load_dwordx batches
        const float* __restrict__ xr =
            X + (size_t)__builtin_amdgcn_readfirstlane(row) * 64;
        float acc = 0.f;
#pragma unroll
        for (int k = 0; k < 64; k++) acc = fmaf(xr[k], w[k], acc);
        if (lane < FP) H[(size_t)row * FP + lane] = acc;  // pads store 0 (w pad)
        float ps = (lane < FP) ? acc * av : 0.f;
        float pd = (lane < FP) ? acc * dv : 0.f;
        for (int o = 32; o > 0; o >>= 1) {
            ps += __shfl_xor(ps, o, 64);
            pd += __shfl_xor(pd, o, 64);
        }
        if (lane == 0) {
            asb[row] = ps;
            adb[row] = pd;
        }
    }
}

// ---------------- Aggregation: segment softmax + weighted gather-sum -------
// One wave per dst node; lane covers feature lf. Edge loop unroll-jammed by
// 4 (4 gathers in flight). All shfl loops have wave-uniform trip counts.
template <int FP>
__global__ __launch_bounds__(256) void k_agg(
    const float* __restrict__ H, const float* __restrict__ asb,
    const float* __restrict__ adb, const float* __restrict__ bias,
    const int* __restrict__ rowptr, const int* __restrict__ csr,
    int N, int Freal, float* __restrict__ out, int mode) {
    int lane = threadIdx.x & 63;
    int node = (blockIdx.x * blockDim.x + threadIdx.x) >> 6;
    if (node >= N) return;
    int start = rowptr[node];
    int end = rowptr[node + 1];
    int deg = end - start;
    float ad = adb[node];
    int lf = lane & (FP - 1);

    const float NEG_INF = -__builtin_inff();
    float acc = 0.f;
    float dsum = 0.f;

    if (deg <= 64) {
        int s = 0;
        float e = NEG_INF;
        if (lane < deg) {
            s = csr[start + lane];
            float t = asb[s] + ad;
            e = (t > 0.f) ? t : NEG_SLOPE * t;
        }
        float m = e;
        for (int o = 32; o > 0; o >>= 1) m = fmaxf(m, __shfl_xor(m, o, 64));
        float p = (lane < deg) ? __expf(e - m) : 0.f;
        dsum = p;
        int j = 0;
        for (; j + 4 <= deg; j += 4) {
            float p0 = __shfl(p, j, 64), p1 = __shfl(p, j + 1, 64);
            float p2 = __shfl(p, j + 2, 64), p3 = __shfl(p, j + 3, 64);
            int q0 = __shfl(s, j, 64), q1 = __shfl(s, j + 1, 64);
            int q2 = __shfl(s, j + 2, 64), q3 = __shfl(s, j + 3, 64);
            float r0 = H[(size_t)q0 * FP + lf];
            float r1 = H[(size_t)q1 * FP + lf];
            float r2 = H[(size_t)q2 * FP + lf];
            float r3 = H[(size_t)q3 * FP + lf];
            acc = fmaf(p0, r0, acc);
            acc = fmaf(p1, r1, acc);
            acc = fmaf(p2, r2, acc);
            acc = fmaf(p3, r3, acc);
        }
        for (; j < deg; j++) {
            float pj = __shfl(p, j, 64);
            int sj = __shfl(s, j, 64);
            acc = fmaf(pj, H[(size_t)sj * FP + lf], acc);
        }
    } else {
        float m = NEG_INF;
        for (int base = start; base < end; base += 64) {
            int i = base + lane;
            if (i < end) {
                float t = asb[csr[i]] + ad;
                float e = (t > 0.f) ? t : NEG_SLOPE * t;
                m = fmaxf(m, e);
            }
        }
        for (int o = 32; o > 0; o >>= 1) m = fmaxf(m, __shfl_xor(m, o, 64));
        for (int base = start; base < end; base += 64) {
            int i = base + lane;
            int cnt = min(64, end - base);
            int s = 0;
            float p = 0.f;
            if (i < end) {
                s = csr[i];
                float t = asb[s] + ad;
                float e = (t > 0.f) ? t : NEG_SLOPE * t;
                p = __expf(e - m);
            }
            dsum += p;
            int j = 0;
            for (; j + 4 <= cnt; j += 4) {
                float p0 = __shfl(p, j, 64), p1 = __shfl(p, j + 1, 64);
                float p2 = __shfl(p, j + 2, 64), p3 = __shfl(p, j + 3, 64);
                int q0 = __shfl(s, j, 64), q1 = __shfl(s, j + 1, 64);
                int q2 = __shfl(s, j + 2, 64), q3 = __shfl(s, j + 3, 64);
                float r0 = H[(size_t)q0 * FP + lf];
                float r1 = H[(size_t)q1 * FP + lf];
                float r2 = H[(size_t)q2 * FP + lf];
                float r3 = H[(size_t)q3 * FP + lf];
                acc = fmaf(p0, r0, acc);
                acc = fmaf(p1, r1, acc);
                acc = fmaf(p2, r2, acc);
                acc = fmaf(p3, r3, acc);
            }
            for (; j < cnt; j++) {
                float pj = __shfl(p, j, 64);
                int sj = __shfl(s, j, 64);
                acc = fmaf(pj, H[(size_t)sj * FP + lf], acc);
            }
        }
    }
    for (int o = 32; o > 0; o >>= 1) dsum += __shfl_xor(dsum, o, 64);

    float b = (lf < Freal) ? bias[lf] : 0.f;
    float z = acc / dsum + b;

    if (mode == 0) {
        if (lane < FP) out[(size_t)node * FP + lane] = fmaxf(z, 0.f);
    } else {
        float zz = (lane < Freal) ? z : NEG_INF;
        float zm = zz;
        for (int o = 32; o > 0; o >>= 1) zm = fmaxf(zm, __shfl_xor(zm, o, 64));
        float ez = (lane < Freal) ? __expf(zz - zm) : 0.f;
        float es = ez;
        for (int o = 32; o > 0; o >>= 1) es += __shfl_xor(es, o, 64);
        if (lane < Freal) out[(size_t)node * Freal + lane] = zz - zm - __logf(es);
    }
}

// ---------------------------------------------------------------------------
extern "C" void kernel_launch(void* const* d_in, const int* in_sizes, int n_in,
                              void* d_out, int out_size, void* d_ws, size_t ws_size,
                              hipStream_t stream) {
    const float* x = (const float*)d_in[0];
    const int* ei = (const int*)d_in[1];
    const float* W1 = (const float*)d_in[2];
    const float* a1s = (const float*)d_in[3];
    const float* a1d = (const float*)d_in[4];
    const float* b1 = (const float*)d_in[5];
    const float* W2 = (const float*)d_in[6];
    const float* a2s = (const float*)d_in[7];
    const float* a2d = (const float*)d_in[8];
    const float* b2 = (const float*)d_in[9];
    const float* W3 = (const float*)d_in[10];
    const float* a3s = (const float*)d_in[11];
    const float* a3d = (const float*)d_in[12];
    const float* b3 = (const float*)d_in[13];

    const int N = in_sizes[0] / 64;
    const int E = in_sizes[1] / 2;
    const int Etot = E + N;
    const int nb = (N + BKT_SZ - 1) >> BKT_BITS;  // buckets of 512 nodes
    const int* srcv = ei;
    const int* dstv = ei + E;

    // workspace carve (256B aligned)
    size_t off = 0;
    char* base = (char*)d_ws;
    auto carve = [&](size_t bytes) -> void* {
        void* p = base + off;
        off = (off + bytes + 255) & ~(size_t)255;
        return p;
    };
    int* bcount = (int*)carve((size_t)(nb + 1) * 4);
    int* ebase = (int*)carve((size_t)(nb + 1) * 4);
    int* gcur = (int*)carve((size_t)nb * 4);
    int* rowptr = (int*)carve((size_t)(N + 1) * 4);
    int* csr = (int*)carve((size_t)Etot * 4);
    float* asb = (float*)carve((size_t)N * 4);
    float* adb = (float*)carve((size_t)N * 4);
    float* bufA = (float*)carve((size_t)N * 64 * 4);
    float* bufB = (float*)carve((size_t)N * 64 * 4);
    float* bufC = (float*)carve((size_t)N * 16 * 4);
    int* ebuf = (int*)bufA;  // alias: ebuf only live before layer-1 GEMM

    // ---- CSR build (bucket sort) ----
    k_zero<<<(nb + 255) / 256, 256, 0, stream>>>(bcount, nb);
    k_hist<<<512, 256, 0, stream>>>(dstv, E, nb, bcount);
    k_bscan<<<1, BKT_SZ, 0, stream>>>(bcount, nb, E, N, ebase, gcur, rowptr);
    k_bscatter<<<(E + 8191) / 8192, 1024, 0, stream>>>(srcv, dstv, E, nb, gcur, ebuf);
    k_bcsr<<<nb, BKT_SZ, 0, stream>>>(ebuf, ebase, N, rowptr, csr);

    const int aggBlocks = (N + 3) / 4;  // 4 waves/block, wave-per-node

    // ---- layer 1 ----
    k_gemm<64><<<1024, 256, 0, stream>>>(x, W1, a1s, a1d, N, 64, bufA, asb, adb);
    k_agg<64><<<aggBlocks, 256, 0, stream>>>(bufA, asb, adb, b1, rowptr, csr, N, 64, bufB, 0);
    // ---- layer 2 ----
    k_gemm<64><<<1024, 256, 0, stream>>>(bufB, W2, a2s, a2d, N, 64, bufA, asb, adb);
    k_agg<64><<<aggBlocks, 256, 0, stream>>>(bufA, asb, adb, b2, rowptr, csr, N, 64, bufB, 0);
    // ---- layer 3 ----
    k_gemm<16><<<1024, 256, 0, stream>>>(bufB, W3, a3s, a3d, N, 10, bufC, asb, adb);
    k_agg<16><<<aggBlocks, 256, 0, stream>>>(bufC, asb, adb, b3, rowptr, csr, N, 10,
                                             (float*)d_out, 1);
}

// Round 6
// 431.951 us; speedup vs baseline: 2.1183x; 1.0445x over previous
//
#include <hip/hip_runtime.h>
#include <math.h>

// ---------------------------------------------------------------------------
// NodeClsGAT: 3-layer GATConv (single head, PyG defaults) on MI355X.
// CSR build via 2-level bucket sort (R2). GEMM: R5 scalar-x/VGPR-W (zero LDS).
// R6: k_agg gather restructured — 16-lane groups each fetch one edge's H row
// as float4 (1 dwordx4 per 4 edges, 4x MLP). R3's version of this FAILED
// because the group loop had a divergent trip count with __shfl inside; here
// the jb-loop is wave-uniform, shuffles are unconditional, and overshoot
// groups FMA with p=0 (s=0 keeps addresses valid). Scores phase unchanged.
// ---------------------------------------------------------------------------

#define NEG_SLOPE 0.2f
#define BKT_BITS 9          // 512 nodes per bucket; supports N <= 262144
#define BKT_SZ   512
#define PACK_SRC_BITS 20    // src < 2^20 (N = 100000)

// ---------------- CSR build: pass A — bucket histogram ----------------
__global__ void k_zero(int* p, int n) {
    int i = blockIdx.x * blockDim.x + threadIdx.x;
    if (i < n) p[i] = 0;
}

__global__ __launch_bounds__(256) void k_hist(const int* __restrict__ dst, int E,
                                              int nb, int* __restrict__ bcount) {
    __shared__ int h[BKT_SZ];
    for (int i = threadIdx.x; i < nb; i += 256) h[i] = 0;
    __syncthreads();
    for (int i = blockIdx.x * 256 + threadIdx.x; i < E; i += gridDim.x * 256)
        atomicAdd(&h[dst[i] >> BKT_BITS], 1);
    __syncthreads();
    for (int i = threadIdx.x; i < nb; i += 256)
        if (h[i]) atomicAdd(&bcount[i], h[i]);
}

// ---------------- pass A2 — scan bucket counts (single block) ----------
__global__ __launch_bounds__(512) void k_bscan(const int* __restrict__ bcount, int nb,
                                               int E, int N, int* __restrict__ ebase,
                                               int* __restrict__ gcur,
                                               int* __restrict__ rowptr) {
    __shared__ int sm[BKT_SZ];
    int t = threadIdx.x;
    int v = (t < nb) ? bcount[t] : 0;
    sm[t] = v;
    __syncthreads();
    for (int o = 1; o < BKT_SZ; o <<= 1) {
        int tv = (t >= o) ? sm[t - o] : 0;
        __syncthreads();
        sm[t] += tv;
        __syncthreads();
    }
    int excl = sm[t] - v;
    if (t < nb) {
        ebase[t] = excl;
        gcur[t] = excl;
    }
    if (t == nb - 1) ebase[nb] = excl + v;  // == E
    if (t == 0) rowptr[N] = E + N;
}

// ---------------- pass B — rank-scatter packed records into buckets -----
__global__ __launch_bounds__(1024) void k_bscatter(const int* __restrict__ src,
                                                   const int* __restrict__ dst, int E,
                                                   int nb, int* __restrict__ gcur,
                                                   int* __restrict__ ebuf) {
    __shared__ int lc[BKT_SZ];
    __shared__ int gb[BKT_SZ];
    for (int i = threadIdx.x; i < nb; i += 1024) lc[i] = 0;
    __syncthreads();
    int base = blockIdx.x * 8192;
    int bkt[8], rnk[8], pk[8];
#pragma unroll
    for (int j = 0; j < 8; j++) {
        int i = base + j * 1024 + threadIdx.x;
        bkt[j] = -1;
        if (i < E) {
            int d = dst[i];
            int s = src[i];
            int b = d >> BKT_BITS;
            bkt[j] = b;
            rnk[j] = atomicAdd(&lc[b], 1);
            pk[j] = ((d & (BKT_SZ - 1)) << PACK_SRC_BITS) | s;
        }
    }
    __syncthreads();
    for (int b = threadIdx.x; b < nb; b += 1024)
        if (lc[b]) gb[b] = atomicAdd(&gcur[b], lc[b]);
    __syncthreads();
#pragma unroll
    for (int j = 0; j < 8; j++)
        if (bkt[j] >= 0) ebuf[gb[bkt[j]] + rnk[j]] = pk[j];
}

// ---------------- pass C — per-bucket CSR finalize ----------------------
__global__ __launch_bounds__(512) void k_bcsr(const int* __restrict__ ebuf,
                                              const int* __restrict__ ebase, int N,
                                              int* __restrict__ rowptr,
                                              int* __restrict__ csr) {
    __shared__ int cnt[BKT_SZ];
    __shared__ int sm[BKT_SZ];
    int b = blockIdx.x;
    int t = threadIdx.x;
    int n0 = b << BKT_BITS;
    int nn = min(BKT_SZ, N - n0);
    cnt[t] = 0;
    __syncthreads();
    int e0 = ebase[b], e1 = ebase[b + 1];
    for (int i = e0 + t; i < e1; i += BKT_SZ)
        atomicAdd(&cnt[ebuf[i] >> PACK_SRC_BITS], 1);
    __syncthreads();
    int v = cnt[t] + (t < nn ? 1 : 0);  // +1 self-loop slot per valid node
    sm[t] = v;
    __syncthreads();
    for (int o = 1; o < BKT_SZ; o <<= 1) {
        int tv = (t >= o) ? sm[t - o] : 0;
        __syncthreads();
        sm[t] += tv;
        __syncthreads();
    }
    int excl = sm[t] - v;
    int cb = e0 + n0;  // csr base: edges before bucket + self-loops before bucket
    if (t < nn) {
        rowptr[n0 + t] = cb + excl;
        csr[cb + excl] = n0 + t;  // self-loop at slot 0 of the node's segment
    }
    cnt[t] = excl + 1;  // edge cursor (after self-loop)
    __syncthreads();
    for (int i = e0 + t; i < e1; i += BKT_SZ) {
        int p = ebuf[i];
        int dl = p >> PACK_SRC_BITS;
        int pos = atomicAdd(&cnt[dl], 1);
        csr[cb + pos] = p & ((1 << PACK_SRC_BITS) - 1);
    }
}

// ---------------- GEMM: H = X @ W, plus alpha_src/alpha_dst epilogue -------
// R5: wave-per-row; lane holds W[:,lf] in 64 VGPRs; x row read via
// wave-uniform scalar loads; inner loop = 64 v_fma (no LDS ops).
template <int FP>
__global__ __launch_bounds__(256) void k_gemm(
    const float* __restrict__ X, const float* __restrict__ W,
    const float* __restrict__ a_s, const float* __restrict__ a_d,
    int N, int Freal,
    float* __restrict__ H, float* __restrict__ asb, float* __restrict__ adb) {
    int lane = threadIdx.x & 63;
    int lf = lane & (FP - 1);

    float w[64];
#pragma unroll
    for (int k = 0; k < 64; k++)
        w[k] = (lf < Freal) ? W[k * Freal + lf] : 0.f;
    float av = (lf < Freal) ? a_s[lf] : 0.f;
    float dv = (lf < Freal) ? a_d[lf] : 0.f;

    int wid = (blockIdx.x * blockDim.x + threadIdx.x) >> 6;
    int nw = (gridDim.x * blockDim.x) >> 6;

    for (int row = wid; row < N; row += nw) {
        // wave-uniform pointer -> compiler promotes to s_load_dwordx batches
        const float* __restrict__ xr =
            X + (size_t)__builtin_amdgcn_readfirstlane(row) * 64;
        float acc = 0.f;
#pragma unroll
        for (int k = 0; k < 64; k++) acc = fmaf(xr[k], w[k], acc);
        if (lane < FP) H[(size_t)row * FP + lane] = acc;  // pads store 0 (w pad)
        float ps = (lane < FP) ? acc * av : 0.f;
        float pd = (lane < FP) ? acc * dv : 0.f;
        for (int o = 32; o > 0; o >>= 1) {
            ps += __shfl_xor(ps, o, 64);
            pd += __shfl_xor(pd, o, 64);
        }
        if (lane == 0) {
            asb[row] = ps;
            adb[row] = pd;
        }
    }
}

// ---------------- Aggregation: segment softmax + weighted gather-sum -------
// One wave per dst node. Scores phase: R4's proven lanes-over-edges. Gather
// phase: LPR=FP/4-lane groups, group g fetches edge jb+g's H row as float4
// (1 dwordx4 per GRP edges). jb-loop is WAVE-UNIFORM; shuffles unconditional;
// overshoot groups (jb+g >= deg) FMA with p=0 and s=0 (valid address).
// jb+g <= 63 always since jb%GRP==0, jb<deg<=64 (chunk<=64). Cross-group
// butterfly (offsets >= LPR) then lanes 0..LPR-1 hold the full row.
template <int FP>
__global__ __launch_bounds__(256) void k_agg(
    const float* __restrict__ H, const float* __restrict__ asb,
    const float* __restrict__ adb, const float* __restrict__ bias,
    const int* __restrict__ rowptr, const int* __restrict__ csr,
    int N, int Freal, float* __restrict__ out, int mode) {
    constexpr int LPR = FP / 4;   // lanes per row
    constexpr int GRP = 64 / LPR; // edges in flight per iteration
    int lane = threadIdx.x & 63;
    int node = (blockIdx.x * blockDim.x + threadIdx.x) >> 6;
    if (node >= N) return;
    int start = rowptr[node];
    int end = rowptr[node + 1];
    int deg = end - start;
    float ad = adb[node];
    int g = lane / LPR;   // edge-group id
    int fl = lane % LPR;  // float4 slot within row

    const float NEG_INF = -__builtin_inff();
    float4 acc = make_float4(0.f, 0.f, 0.f, 0.f);
    float dsum = 0.f;

    if (deg <= 64) {
        // scores fully in registers (proven R4 structure)
        int s = 0;
        float e = NEG_INF;
        if (lane < deg) {
            s = csr[start + lane];
            float t = asb[s] + ad;
            e = (t > 0.f) ? t : NEG_SLOPE * t;
        }
        float m = e;
        for (int o = 32; o > 0; o >>= 1) m = fmaxf(m, __shfl_xor(m, o, 64));
        float p = (lane < deg) ? __expf(e - m) : 0.f;
        dsum = p;
#pragma unroll 2
        for (int jb = 0; jb < deg; jb += GRP) {  // wave-uniform bound
            int idx = jb + g;                    // <= 63 always
            float pj = __shfl(p, idx, 64);       // 0 for idx >= deg
            int sj = __shfl(s, idx, 64);         // 0 for idx >= deg (valid addr)
            float4 r = ((const float4*)(H + (size_t)sj * FP))[fl];
            acc.x = fmaf(pj, r.x, acc.x);
            acc.y = fmaf(pj, r.y, acc.y);
            acc.z = fmaf(pj, r.z, acc.z);
            acc.w = fmaf(pj, r.w, acc.w);
        }
    } else {
        // slow path (deg > 64, essentially never at mean deg ~17): two-pass
        float m = NEG_INF;
        for (int base = start; base < end; base += 64) {
            int i = base + lane;
            if (i < end) {
                float t = asb[csr[i]] + ad;
                float e = (t > 0.f) ? t : NEG_SLOPE * t;
                m = fmaxf(m, e);
            }
        }
        for (int o = 32; o > 0; o >>= 1) m = fmaxf(m, __shfl_xor(m, o, 64));
        for (int base = start; base < end; base += 64) {
            int i = base + lane;
            int cnt = min(64, end - base);
            int s = 0;
            float p = 0.f;
            if (i < end) {
                s = csr[i];
                float t = asb[s] + ad;
                float e = (t > 0.f) ? t : NEG_SLOPE * t;
                p = __expf(e - m);
            }
            dsum += p;
            for (int jb = 0; jb < cnt; jb += GRP) {  // wave-uniform bound
                int idx = jb + g;
                float pj = __shfl(p, idx, 64);
                int sj = __shfl(s, idx, 64);
                float4 r = ((const float4*)(H + (size_t)sj * FP))[fl];
                acc.x = fmaf(pj, r.x, acc.x);
                acc.y = fmaf(pj, r.y, acc.y);
                acc.z = fmaf(pj, r.z, acc.z);
                acc.w = fmaf(pj, r.w, acc.w);
            }
        }
    }
    for (int o = 32; o > 0; o >>= 1) dsum += __shfl_xor(dsum, o, 64);
    // cross-group butterfly: offsets LPR..32 preserve fl
    for (int o = LPR; o < 64; o <<= 1) {
        acc.x += __shfl_xor(acc.x, o, 64);
        acc.y += __shfl_xor(acc.y, o, 64);
        acc.z += __shfl_xor(acc.z, o, 64);
        acc.w += __shfl_xor(acc.w, o, 64);
    }
    float inv = 1.f / dsum;
    int fbase = fl * 4;

    if (mode == 0) {
        if (lane < LPR) {
            float4 z;
            z.x = fmaxf(fmaf(acc.x, inv, bias[fbase + 0]), 0.f);
            z.y = fmaxf(fmaf(acc.y, inv, bias[fbase + 1]), 0.f);
            z.z = fmaxf(fmaf(acc.z, inv, bias[fbase + 2]), 0.f);
            z.w = fmaxf(fmaf(acc.w, inv, bias[fbase + 3]), 0.f);
            ((float4*)(out + (size_t)node * FP))[fl] = z;
        }
    } else {
        // log_softmax over Freal; lanes 0..LPR-1 form an xor{1,2,..} coset
        float zc[4];
#pragma unroll
        for (int c = 0; c < 4; c++) {
            int f = fbase + c;
            float av = (c == 0) ? acc.x : (c == 1) ? acc.y : (c == 2) ? acc.z : acc.w;
            zc[c] = (f < Freal) ? fmaf(av, inv, bias[f]) : NEG_INF;
        }
        float vm = fmaxf(fmaxf(zc[0], zc[1]), fmaxf(zc[2], zc[3]));
        for (int o = 1; o < LPR; o <<= 1) vm = fmaxf(vm, __shfl_xor(vm, o, 64));
        float es = 0.f;
#pragma unroll
        for (int c = 0; c < 4; c++) es += __expf(zc[c] - vm);
        for (int o = 1; o < LPR; o <<= 1) es += __shfl_xor(es, o, 64);
        float ls = __logf(es);
        if (lane < LPR) {
#pragma unroll
            for (int c = 0; c < 4; c++) {
                int f = fbase + c;
                if (f < Freal) out[(size_t)node * Freal + f] = zc[c] - vm - ls;
            }
        }
    }
}

// ---------------------------------------------------------------------------
extern "C" void kernel_launch(void* const* d_in, const int* in_sizes, int n_in,
                              void* d_out, int out_size, void* d_ws, size_t ws_size,
                              hipStream_t stream) {
    const float* x = (const float*)d_in[0];
    const int* ei = (const int*)d_in[1];
    const float* W1 = (const float*)d_in[2];
    const float* a1s = (const float*)d_in[3];
    const float* a1d = (const float*)d_in[4];
    const float* b1 = (const float*)d_in[5];
    const float* W2 = (const float*)d_in[6];
    const float* a2s = (const float*)d_in[7];
    const float* a2d = (const float*)d_in[8];
    const float* b2 = (const float*)d_in[9];
    const float* W3 = (const float*)d_in[10];
    const float* a3s = (const float*)d_in[11];
    const float* a3d = (const float*)d_in[12];
    const float* b3 = (const float*)d_in[13];

    const int N = in_sizes[0] / 64;
    const int E = in_sizes[1] / 2;
    const int Etot = E + N;
    const int nb = (N + BKT_SZ - 1) >> BKT_BITS;  // buckets of 512 nodes
    const int* srcv = ei;
    const int* dstv = ei + E;

    // workspace carve (256B aligned)
    size_t off = 0;
    char* base = (char*)d_ws;
    auto carve = [&](size_t bytes) -> void* {
        void* p = base + off;
        off = (off + bytes + 255) & ~(size_t)255;
        return p;
    };
    int* bcount = (int*)carve((size_t)(nb + 1) * 4);
    int* ebase = (int*)carve((size_t)(nb + 1) * 4);
    int* gcur = (int*)carve((size_t)nb * 4);
    int* rowptr = (int*)carve((size_t)(N + 1) * 4);
    int* csr = (int*)carve((size_t)Etot * 4);
    float* asb = (float*)carve((size_t)N * 4);
    float* adb = (float*)carve((size_t)N * 4);
    float* bufA = (float*)carve((size_t)N * 64 * 4);
    float* bufB = (float*)carve((size_t)N * 64 * 4);
    float* bufC = (float*)carve((size_t)N * 16 * 4);
    int* ebuf = (int*)bufA;  // alias: ebuf only live before layer-1 GEMM

    // ---- CSR build (bucket sort) ----
    k_zero<<<(nb + 255) / 256, 256, 0, stream>>>(bcount, nb);
    k_hist<<<512, 256, 0, stream>>>(dstv, E, nb, bcount);
    k_bscan<<<1, BKT_SZ, 0, stream>>>(bcount, nb, E, N, ebase, gcur, rowptr);
    k_bscatter<<<(E + 8191) / 8192, 1024, 0, stream>>>(srcv, dstv, E, nb, gcur, ebuf);
    k_bcsr<<<nb, BKT_SZ, 0, stream>>>(ebuf, ebase, N, rowptr, csr);

    const int aggBlocks = (N + 3) / 4;  // 4 waves/block, wave-per-node

    // ---- layer 1 ----
    k_gemm<64><<<1024, 256, 0, stream>>>(x, W1, a1s, a1d, N, 64, bufA, asb, adb);
    k_agg<64><<<aggBlocks, 256, 0, stream>>>(bufA, asb, adb, b1, rowptr, csr, N, 64, bufB, 0);
    // ---- layer 2 ----
    k_gemm<64><<<1024, 256, 0, stream>>>(bufB, W2, a2s, a2d, N, 64, bufA, asb, adb);
    k_agg<64><<<aggBlocks, 256, 0, stream>>>(bufA, asb, adb, b2, rowptr, csr, N, 64, bufB, 0);
    // ---- layer 3 ----
    k_gemm<16><<<1024, 256, 0, stream>>>(bufB, W3, a3s, a3d, N, 10, bufC, asb, adb);
    k_agg<16><<<aggBlocks, 256, 0, stream>>>(bufC, asb, adb, b3, rowptr, csr, N, 10,
                                             (float*)d_out, 1);
}

// Round 7
// 406.840 us; speedup vs baseline: 2.2491x; 1.0617x over previous
//
#include <hip/hip_runtime.h>
#include <math.h>

// ---------------------------------------------------------------------------
// NodeClsGAT: 3-layer GATConv (single head, PyG defaults) on MI355X.
// CSR build via 2-level bucket sort (R2). GEMM: R5 scalar-x/VGPR-W.
// k_agg: R6 lane-group float4... -> R7: H stored as fp16 (_Float16).
// R6 evidence: 4x fewer gather instrs moved agg64 only 75->70us => gather is
// demand-BW-bound (435 MB @ 6.2 TB/s). fp16 H halves bytes/edge (256->128B
// rows); scores, accumulators, and layer outputs stay fp32.
// ---------------------------------------------------------------------------

#define NEG_SLOPE 0.2f
#define BKT_BITS 9          // 512 nodes per bucket; supports N <= 262144
#define BKT_SZ   512
#define PACK_SRC_BITS 20    // src < 2^20 (N = 100000)

typedef _Float16 half4v __attribute__((ext_vector_type(4)));

// ---------------- CSR build: pass A — bucket histogram ----------------
__global__ void k_zero(int* p, int n) {
    int i = blockIdx.x * blockDim.x + threadIdx.x;
    if (i < n) p[i] = 0;
}

__global__ __launch_bounds__(256) void k_hist(const int* __restrict__ dst, int E,
                                              int nb, int* __restrict__ bcount) {
    __shared__ int h[BKT_SZ];
    for (int i = threadIdx.x; i < nb; i += 256) h[i] = 0;
    __syncthreads();
    for (int i = blockIdx.x * 256 + threadIdx.x; i < E; i += gridDim.x * 256)
        atomicAdd(&h[dst[i] >> BKT_BITS], 1);
    __syncthreads();
    for (int i = threadIdx.x; i < nb; i += 256)
        if (h[i]) atomicAdd(&bcount[i], h[i]);
}

// ---------------- pass A2 — scan bucket counts (single block) ----------
__global__ __launch_bounds__(512) void k_bscan(const int* __restrict__ bcount, int nb,
                                               int E, int N, int* __restrict__ ebase,
                                               int* __restrict__ gcur,
                                               int* __restrict__ rowptr) {
    __shared__ int sm[BKT_SZ];
    int t = threadIdx.x;
    int v = (t < nb) ? bcount[t] : 0;
    sm[t] = v;
    __syncthreads();
    for (int o = 1; o < BKT_SZ; o <<= 1) {
        int tv = (t >= o) ? sm[t - o] : 0;
        __syncthreads();
        sm[t] += tv;
        __syncthreads();
    }
    int excl = sm[t] - v;
    if (t < nb) {
        ebase[t] = excl;
        gcur[t] = excl;
    }
    if (t == nb - 1) ebase[nb] = excl + v;  // == E
    if (t == 0) rowptr[N] = E + N;
}

// ---------------- pass B — rank-scatter packed records into buckets -----
__global__ __launch_bounds__(1024) void k_bscatter(const int* __restrict__ src,
                                                   const int* __restrict__ dst, int E,
                                                   int nb, int* __restrict__ gcur,
                                                   int* __restrict__ ebuf) {
    __shared__ int lc[BKT_SZ];
    __shared__ int gb[BKT_SZ];
    for (int i = threadIdx.x; i < nb; i += 1024) lc[i] = 0;
    __syncthreads();
    int base = blockIdx.x * 8192;
    int bkt[8], rnk[8], pk[8];
#pragma unroll
    for (int j = 0; j < 8; j++) {
        int i = base + j * 1024 + threadIdx.x;
        bkt[j] = -1;
        if (i < E) {
            int d = dst[i];
            int s = src[i];
            int b = d >> BKT_BITS;
            bkt[j] = b;
            rnk[j] = atomicAdd(&lc[b], 1);
            pk[j] = ((d & (BKT_SZ - 1)) << PACK_SRC_BITS) | s;
        }
    }
    __syncthreads();
    for (int b = threadIdx.x; b < nb; b += 1024)
        if (lc[b]) gb[b] = atomicAdd(&gcur[b], lc[b]);
    __syncthreads();
#pragma unroll
    for (int j = 0; j < 8; j++)
        if (bkt[j] >= 0) ebuf[gb[bkt[j]] + rnk[j]] = pk[j];
}

// ---------------- pass C — per-bucket CSR finalize ----------------------
__global__ __launch_bounds__(512) void k_bcsr(const int* __restrict__ ebuf,
                                              const int* __restrict__ ebase, int N,
                                              int* __restrict__ rowptr,
                                              int* __restrict__ csr) {
    __shared__ int cnt[BKT_SZ];
    __shared__ int sm[BKT_SZ];
    int b = blockIdx.x;
    int t = threadIdx.x;
    int n0 = b << BKT_BITS;
    int nn = min(BKT_SZ, N - n0);
    cnt[t] = 0;
    __syncthreads();
    int e0 = ebase[b], e1 = ebase[b + 1];
    for (int i = e0 + t; i < e1; i += BKT_SZ)
        atomicAdd(&cnt[ebuf[i] >> PACK_SRC_BITS], 1);
    __syncthreads();
    int v = cnt[t] + (t < nn ? 1 : 0);  // +1 self-loop slot per valid node
    sm[t] = v;
    __syncthreads();
    for (int o = 1; o < BKT_SZ; o <<= 1) {
        int tv = (t >= o) ? sm[t - o] : 0;
        __syncthreads();
        sm[t] += tv;
        __syncthreads();
    }
    int excl = sm[t] - v;
    int cb = e0 + n0;  // csr base: edges before bucket + self-loops before bucket
    if (t < nn) {
        rowptr[n0 + t] = cb + excl;
        csr[cb + excl] = n0 + t;  // self-loop at slot 0 of the node's segment
    }
    cnt[t] = excl + 1;  // edge cursor (after self-loop)
    __syncthreads();
    for (int i = e0 + t; i < e1; i += BKT_SZ) {
        int p = ebuf[i];
        int dl = p >> PACK_SRC_BITS;
        int pos = atomicAdd(&cnt[dl], 1);
        csr[cb + pos] = p & ((1 << PACK_SRC_BITS) - 1);
    }
}

// ---------------- GEMM: H = X @ W (fp16 out), alpha epilogue fp32 ----------
// R5 structure: wave-per-row; lane holds W[:,lf] in 64 VGPRs; x row read via
// wave-uniform scalar loads; inner loop = 64 v_fma (no LDS ops).
template <int FP>
__global__ __launch_bounds__(256) void k_gemm(
    const float* __restrict__ X, const float* __restrict__ W,
    const float* __restrict__ a_s, const float* __restrict__ a_d,
    int N, int Freal,
    _Float16* __restrict__ H, float* __restrict__ asb, float* __restrict__ adb) {
    int lane = threadIdx.x & 63;
    int lf = lane & (FP - 1);

    float w[64];
#pragma unroll
    for (int k = 0; k < 64; k++)
        w[k] = (lf < Freal) ? W[k * Freal + lf] : 0.f;
    float av = (lf < Freal) ? a_s[lf] : 0.f;
    float dv = (lf < Freal) ? a_d[lf] : 0.f;

    int wid = (blockIdx.x * blockDim.x + threadIdx.x) >> 6;
    int nw = (gridDim.x * blockDim.x) >> 6;

    for (int row = wid; row < N; row += nw) {
        // wave-uniform pointer -> compiler promotes to s_load_dwordx batches
        const float* __restrict__ xr =
            X + (size_t)__builtin_amdgcn_readfirstlane(row) * 64;
        float acc = 0.f;
#pragma unroll
        for (int k = 0; k < 64; k++) acc = fmaf(xr[k], w[k], acc);
        if (lane < FP) H[(size_t)row * FP + lane] = (_Float16)acc;  // pads = 0
        float ps = (lane < FP) ? acc * av : 0.f;
        float pd = (lane < FP) ? acc * dv : 0.f;
        for (int o = 32; o > 0; o >>= 1) {
            ps += __shfl_xor(ps, o, 64);
            pd += __shfl_xor(pd, o, 64);
        }
        if (lane == 0) {
            asb[row] = ps;
            adb[row] = pd;
        }
    }
}

// ---------------- Aggregation: segment softmax + weighted gather-sum -------
// One wave per dst node. Scores fp32 (R4 structure). Gather: LPR=FP/4-lane
// groups, group g fetches edge jb+g's fp16 H row as half4 (8 B/lane).
// jb-loop is WAVE-UNIFORM; shuffles unconditional; overshoot groups FMA with
// p=0, s=0 (valid address). Cross-group butterfly then lanes 0..LPR-1 hold
// the full fp32 row.
template <int FP>
__global__ __launch_bounds__(256) void k_agg(
    const _Float16* __restrict__ H, const float* __restrict__ asb,
    const float* __restrict__ adb, const float* __restrict__ bias,
    const int* __restrict__ rowptr, const int* __restrict__ csr,
    int N, int Freal, float* __restrict__ out, int mode) {
    constexpr int LPR = FP / 4;   // lanes per row
    constexpr int GRP = 64 / LPR; // edges in flight per iteration
    int lane = threadIdx.x & 63;
    int node = (blockIdx.x * blockDim.x + threadIdx.x) >> 6;
    if (node >= N) return;
    int start = rowptr[node];
    int end = rowptr[node + 1];
    int deg = end - start;
    float ad = adb[node];
    int g = lane / LPR;   // edge-group id
    int fl = lane % LPR;  // half4 slot within row

    const float NEG_INF = -__builtin_inff();
    float4 acc = make_float4(0.f, 0.f, 0.f, 0.f);
    float dsum = 0.f;

    if (deg <= 64) {
        // scores fully in registers (proven R4 structure)
        int s = 0;
        float e = NEG_INF;
        if (lane < deg) {
            s = csr[start + lane];
            float t = asb[s] + ad;
            e = (t > 0.f) ? t : NEG_SLOPE * t;
        }
        float m = e;
        for (int o = 32; o > 0; o >>= 1) m = fmaxf(m, __shfl_xor(m, o, 64));
        float p = (lane < deg) ? __expf(e - m) : 0.f;
        dsum = p;
#pragma unroll 2
        for (int jb = 0; jb < deg; jb += GRP) {  // wave-uniform bound
            int idx = jb + g;                    // <= 63 always
            float pj = __shfl(p, idx, 64);       // 0 for idx >= deg
            int sj = __shfl(s, idx, 64);         // 0 for idx >= deg (valid addr)
            half4v r = ((const half4v*)(H + (size_t)sj * FP))[fl];
            acc.x = fmaf(pj, (float)r.x, acc.x);
            acc.y = fmaf(pj, (float)r.y, acc.y);
            acc.z = fmaf(pj, (float)r.z, acc.z);
            acc.w = fmaf(pj, (float)r.w, acc.w);
        }
    } else {
        // slow path (deg > 64, essentially never at mean deg ~17): two-pass
        float m = NEG_INF;
        for (int base = start; base < end; base += 64) {
            int i = base + lane;
            if (i < end) {
                float t = asb[csr[i]] + ad;
                float e = (t > 0.f) ? t : NEG_SLOPE * t;
                m = fmaxf(m, e);
            }
        }
        for (int o = 32; o > 0; o >>= 1) m = fmaxf(m, __shfl_xor(m, o, 64));
        for (int base = start; base < end; base += 64) {
            int i = base + lane;
            int cnt = min(64, end - base);
            int s = 0;
            float p = 0.f;
            if (i < end) {
                s = csr[i];
                float t = asb[s] + ad;
                float e = (t > 0.f) ? t : NEG_SLOPE * t;
                p = __expf(e - m);
            }
            dsum += p;
            for (int jb = 0; jb < cnt; jb += GRP) {  // wave-uniform bound
                int idx = jb + g;
                float pj = __shfl(p, idx, 64);
                int sj = __shfl(s, idx, 64);
                half4v r = ((const half4v*)(H + (size_t)sj * FP))[fl];
                acc.x = fmaf(pj, (float)r.x, acc.x);
                acc.y = fmaf(pj, (float)r.y, acc.y);
                acc.z = fmaf(pj, (float)r.z, acc.z);
                acc.w = fmaf(pj, (float)r.w, acc.w);
            }
        }
    }
    for (int o = 32; o > 0; o >>= 1) dsum += __shfl_xor(dsum, o, 64);
    // cross-group butterfly: offsets LPR..32 preserve fl
    for (int o = LPR; o < 64; o <<= 1) {
        acc.x += __shfl_xor(acc.x, o, 64);
        acc.y += __shfl_xor(acc.y, o, 64);
        acc.z += __shfl_xor(acc.z, o, 64);
        acc.w += __shfl_xor(acc.w, o, 64);
    }
    float inv = 1.f / dsum;
    int fbase = fl * 4;

    if (mode == 0) {
        if (lane < LPR) {
            float4 z;
            z.x = fmaxf(fmaf(acc.x, inv, bias[fbase + 0]), 0.f);
            z.y = fmaxf(fmaf(acc.y, inv, bias[fbase + 1]), 0.f);
            z.z = fmaxf(fmaf(acc.z, inv, bias[fbase + 2]), 0.f);
            z.w = fmaxf(fmaf(acc.w, inv, bias[fbase + 3]), 0.f);
            ((float4*)(out + (size_t)node * FP))[fl] = z;
        }
    } else {
        // log_softmax over Freal; lanes 0..LPR-1 form an xor{1,2,..} coset
        float zc[4];
#pragma unroll
        for (int c = 0; c < 4; c++) {
            int f = fbase + c;
            float av = (c == 0) ? acc.x : (c == 1) ? acc.y : (c == 2) ? acc.z : acc.w;
            zc[c] = (f < Freal) ? fmaf(av, inv, bias[f]) : NEG_INF;
        }
        float vm = fmaxf(fmaxf(zc[0], zc[1]), fmaxf(zc[2], zc[3]));
        for (int o = 1; o < LPR; o <<= 1) vm = fmaxf(vm, __shfl_xor(vm, o, 64));
        float es = 0.f;
#pragma unroll
        for (int c = 0; c < 4; c++) es += __expf(zc[c] - vm);
        for (int o = 1; o < LPR; o <<= 1) es += __shfl_xor(es, o, 64);
        float ls = __logf(es);
        if (lane < LPR) {
#pragma unroll
            for (int c = 0; c < 4; c++) {
                int f = fbase + c;
                if (f < Freal) out[(size_t)node * Freal + f] = zc[c] - vm - ls;
            }
        }
    }
}

// ---------------------------------------------------------------------------
extern "C" void kernel_launch(void* const* d_in, const int* in_sizes, int n_in,
                              void* d_out, int out_size, void* d_ws, size_t ws_size,
                              hipStream_t stream) {
    const float* x = (const float*)d_in[0];
    const int* ei = (const int*)d_in[1];
    const float* W1 = (const float*)d_in[2];
    const float* a1s = (const float*)d_in[3];
    const float* a1d = (const float*)d_in[4];
    const float* b1 = (const float*)d_in[5];
    const float* W2 = (const float*)d_in[6];
    const float* a2s = (const float*)d_in[7];
    const float* a2d = (const float*)d_in[8];
    const float* b2 = (const float*)d_in[9];
    const float* W3 = (const float*)d_in[10];
    const float* a3s = (const float*)d_in[11];
    const float* a3d = (const float*)d_in[12];
    const float* b3 = (const float*)d_in[13];

    const int N = in_sizes[0] / 64;
    const int E = in_sizes[1] / 2;
    const int Etot = E + N;
    const int nb = (N + BKT_SZ - 1) >> BKT_BITS;  // buckets of 512 nodes
    const int* srcv = ei;
    const int* dstv = ei + E;

    // workspace carve (256B aligned)
    size_t off = 0;
    char* base = (char*)d_ws;
    auto carve = [&](size_t bytes) -> void* {
        void* p = base + off;
        off = (off + bytes + 255) & ~(size_t)255;
        return p;
    };
    int* bcount = (int*)carve((size_t)(nb + 1) * 4);
    int* ebase = (int*)carve((size_t)(nb + 1) * 4);
    int* gcur = (int*)carve((size_t)nb * 4);
    int* rowptr = (int*)carve((size_t)(N + 1) * 4);
    int* csr = (int*)carve((size_t)Etot * 4);
    float* asb = (float*)carve((size_t)N * 4);
    float* adb = (float*)carve((size_t)N * 4);
    _Float16* hA = (_Float16*)carve((size_t)N * 64 * 2);  // fp16 H (layers 1,2)
    float* fB = (float*)carve((size_t)N * 64 * 4);        // fp32 agg out / X
    _Float16* hC = (_Float16*)carve((size_t)N * 16 * 2);  // fp16 H (layer 3)
    int* ebuf = (int*)hA;  // alias: ebuf (E*4 <= N*64*2) only live pre-layer-1

    // ---- CSR build (bucket sort) ----
    k_zero<<<(nb + 255) / 256, 256, 0, stream>>>(bcount, nb);
    k_hist<<<512, 256, 0, stream>>>(dstv, E, nb, bcount);
    k_bscan<<<1, BKT_SZ, 0, stream>>>(bcount, nb, E, N, ebase, gcur, rowptr);
    k_bscatter<<<(E + 8191) / 8192, 1024, 0, stream>>>(srcv, dstv, E, nb, gcur, ebuf);
    k_bcsr<<<nb, BKT_SZ, 0, stream>>>(ebuf, ebase, N, rowptr, csr);

    const int aggBlocks = (N + 3) / 4;  // 4 waves/block, wave-per-node

    // ---- layer 1 ----
    k_gemm<64><<<1024, 256, 0, stream>>>(x, W1, a1s, a1d, N, 64, hA, asb, adb);
    k_agg<64><<<aggBlocks, 256, 0, stream>>>(hA, asb, adb, b1, rowptr, csr, N, 64, fB, 0);
    // ---- layer 2 ----
    k_gemm<64><<<1024, 256, 0, stream>>>(fB, W2, a2s, a2d, N, 64, hA, asb, adb);
    k_agg<64><<<aggBlocks, 256, 0, stream>>>(hA, asb, adb, b2, rowptr, csr, N, 64, fB, 0);
    // ---- layer 3 ----
    k_gemm<16><<<1024, 256, 0, stream>>>(fB, W3, a3s, a3d, N, 10, hC, asb, adb);
    k_agg<16><<<aggBlocks, 256, 0, stream>>>(hC, asb, adb, b3, rowptr, csr, N, 10,
                                             (float*)d_out, 1);
}

// Round 8
// 385.424 us; speedup vs baseline: 2.3741x; 1.0556x over previous
//
#include <hip/hip_runtime.h>
#include <math.h>
#include <type_traits>

// ---------------------------------------------------------------------------
// NodeClsGAT: 3-layer GATConv (single head, PyG defaults) on MI355X.
// CSR build via 2-level bucket sort (R2). GEMM: R5 scalar-x/VGPR-W.
// k_agg R8: DUAL-NODE waves — each 32-lane half handles one dst node
// (P(deg<=32)~0.9998), halving per-node wave overhead and doubling chain
// concurrency; gathers widened to half8 (16 B/lane, LPR=8). Wave-uniform
// loop bound degm=max(degA,degB); all shuffles unconditional and in-half;
// overshoot lanes use p=0/s=0 (R6 trick). degm>32 falls back (wave-uniform)
// to R4's proven two-pass whole-wave path per node.
// ---------------------------------------------------------------------------

#define NEG_SLOPE 0.2f
#define BKT_BITS 9          // 512 nodes per bucket; supports N <= 262144
#define BKT_SZ   512
#define PACK_SRC_BITS 20    // src < 2^20 (N = 100000)

typedef _Float16 h8v __attribute__((ext_vector_type(8)));
typedef _Float16 h4v __attribute__((ext_vector_type(4)));

// ---------------- CSR build: pass A — bucket histogram ----------------
__global__ void k_zero(int* p, int n) {
    int i = blockIdx.x * blockDim.x + threadIdx.x;
    if (i < n) p[i] = 0;
}

__global__ __launch_bounds__(256) void k_hist(const int* __restrict__ dst, int E,
                                              int nb, int* __restrict__ bcount) {
    __shared__ int h[BKT_SZ];
    for (int i = threadIdx.x; i < nb; i += 256) h[i] = 0;
    __syncthreads();
    for (int i = blockIdx.x * 256 + threadIdx.x; i < E; i += gridDim.x * 256)
        atomicAdd(&h[dst[i] >> BKT_BITS], 1);
    __syncthreads();
    for (int i = threadIdx.x; i < nb; i += 256)
        if (h[i]) atomicAdd(&bcount[i], h[i]);
}

// ---------------- pass A2 — scan bucket counts (single block) ----------
__global__ __launch_bounds__(512) void k_bscan(const int* __restrict__ bcount, int nb,
                                               int E, int N, int* __restrict__ ebase,
                                               int* __restrict__ gcur,
                                               int* __restrict__ rowptr) {
    __shared__ int sm[BKT_SZ];
    int t = threadIdx.x;
    int v = (t < nb) ? bcount[t] : 0;
    sm[t] = v;
    __syncthreads();
    for (int o = 1; o < BKT_SZ; o <<= 1) {
        int tv = (t >= o) ? sm[t - o] : 0;
        __syncthreads();
        sm[t] += tv;
        __syncthreads();
    }
    int excl = sm[t] - v;
    if (t < nb) {
        ebase[t] = excl;
        gcur[t] = excl;
    }
    if (t == nb - 1) ebase[nb] = excl + v;  // == E
    if (t == 0) rowptr[N] = E + N;
}

// ---------------- pass B — rank-scatter packed records into buckets -----
__global__ __launch_bounds__(1024) void k_bscatter(const int* __restrict__ src,
                                                   const int* __restrict__ dst, int E,
                                                   int nb, int* __restrict__ gcur,
                                                   int* __restrict__ ebuf) {
    __shared__ int lc[BKT_SZ];
    __shared__ int gb[BKT_SZ];
    for (int i = threadIdx.x; i < nb; i += 1024) lc[i] = 0;
    __syncthreads();
    int base = blockIdx.x * 8192;
    int bkt[8], rnk[8], pk[8];
#pragma unroll
    for (int j = 0; j < 8; j++) {
        int i = base + j * 1024 + threadIdx.x;
        bkt[j] = -1;
        if (i < E) {
            int d = dst[i];
            int s = src[i];
            int b = d >> BKT_BITS;
            bkt[j] = b;
            rnk[j] = atomicAdd(&lc[b], 1);
            pk[j] = ((d & (BKT_SZ - 1)) << PACK_SRC_BITS) | s;
        }
    }
    __syncthreads();
    for (int b = threadIdx.x; b < nb; b += 1024)
        if (lc[b]) gb[b] = atomicAdd(&gcur[b], lc[b]);
    __syncthreads();
#pragma unroll
    for (int j = 0; j < 8; j++)
        if (bkt[j] >= 0) ebuf[gb[bkt[j]] + rnk[j]] = pk[j];
}

// ---------------- pass C — per-bucket CSR finalize ----------------------
__global__ __launch_bounds__(512) void k_bcsr(const int* __restrict__ ebuf,
                                              const int* __restrict__ ebase, int N,
                                              int* __restrict__ rowptr,
                                              int* __restrict__ csr) {
    __shared__ int cnt[BKT_SZ];
    __shared__ int sm[BKT_SZ];
    int b = blockIdx.x;
    int t = threadIdx.x;
    int n0 = b << BKT_BITS;
    int nn = min(BKT_SZ, N - n0);
    cnt[t] = 0;
    __syncthreads();
    int e0 = ebase[b], e1 = ebase[b + 1];
    for (int i = e0 + t; i < e1; i += BKT_SZ)
        atomicAdd(&cnt[ebuf[i] >> PACK_SRC_BITS], 1);
    __syncthreads();
    int v = cnt[t] + (t < nn ? 1 : 0);  // +1 self-loop slot per valid node
    sm[t] = v;
    __syncthreads();
    for (int o = 1; o < BKT_SZ; o <<= 1) {
        int tv = (t >= o) ? sm[t - o] : 0;
        __syncthreads();
        sm[t] += tv;
        __syncthreads();
    }
    int excl = sm[t] - v;
    int cb = e0 + n0;  // csr base: edges before bucket + self-loops before bucket
    if (t < nn) {
        rowptr[n0 + t] = cb + excl;
        csr[cb + excl] = n0 + t;  // self-loop at slot 0 of the node's segment
    }
    cnt[t] = excl + 1;  // edge cursor (after self-loop)
    __syncthreads();
    for (int i = e0 + t; i < e1; i += BKT_SZ) {
        int p = ebuf[i];
        int dl = p >> PACK_SRC_BITS;
        int pos = atomicAdd(&cnt[dl], 1);
        csr[cb + pos] = p & ((1 << PACK_SRC_BITS) - 1);
    }
}

// ---------------- GEMM: H = X @ W (fp16 out), alpha epilogue fp32 ----------
// R5 structure: wave-per-row; lane holds W[:,lf] in 64 VGPRs; x row read via
// wave-uniform scalar loads; inner loop = 64 v_fma (no LDS ops).
template <int FP>
__global__ __launch_bounds__(256) void k_gemm(
    const float* __restrict__ X, const float* __restrict__ W,
    const float* __restrict__ a_s, const float* __restrict__ a_d,
    int N, int Freal,
    _Float16* __restrict__ H, float* __restrict__ asb, float* __restrict__ adb) {
    int lane = threadIdx.x & 63;
    int lf = lane & (FP - 1);

    float w[64];
#pragma unroll
    for (int k = 0; k < 64; k++)
        w[k] = (lf < Freal) ? W[k * Freal + lf] : 0.f;
    float av = (lf < Freal) ? a_s[lf] : 0.f;
    float dv = (lf < Freal) ? a_d[lf] : 0.f;

    int wid = (blockIdx.x * blockDim.x + threadIdx.x) >> 6;
    int nw = (gridDim.x * blockDim.x) >> 6;

    for (int row = wid; row < N; row += nw) {
        // wave-uniform pointer -> compiler promotes to s_load_dwordx batches
        const float* __restrict__ xr =
            X + (size_t)__builtin_amdgcn_readfirstlane(row) * 64;
        float acc = 0.f;
#pragma unroll
        for (int k = 0; k < 64; k++) acc = fmaf(xr[k], w[k], acc);
        if (lane < FP) H[(size_t)row * FP + lane] = (_Float16)acc;  // pads = 0
        float ps = (lane < FP) ? acc * av : 0.f;
        float pd = (lane < FP) ? acc * dv : 0.f;
        for (int o = 32; o > 0; o >>= 1) {
            ps += __shfl_xor(ps, o, 64);
            pd += __shfl_xor(pd, o, 64);
        }
        if (lane == 0) {
            asb[row] = ps;
            adb[row] = pd;
        }
    }
}

// ---------------- slow-path agg (R4-proven, whole wave, any deg) -----------
template <int FP>
__device__ __forceinline__ void agg_slow(
    int node, const _Float16* __restrict__ H, const float* __restrict__ asb,
    const float* __restrict__ adb, const float* __restrict__ bias,
    const int* __restrict__ rowptr, const int* __restrict__ csr,
    int N, int Freal, float* __restrict__ out, int mode, int lane) {
    if (node >= N) return;
    int start = rowptr[node];
    int end = rowptr[node + 1];
    float ad = adb[node];
    int lf = lane & (FP - 1);
    const float NEG_INF = -__builtin_inff();

    float m = NEG_INF;
    for (int base = start; base < end; base += 64) {
        int i = base + lane;
        if (i < end) {
            float t = asb[csr[i]] + ad;
            float e = (t > 0.f) ? t : NEG_SLOPE * t;
            m = fmaxf(m, e);
        }
    }
    for (int o = 32; o > 0; o >>= 1) m = fmaxf(m, __shfl_xor(m, o, 64));
    float dsum = 0.f, acc = 0.f;
    for (int base = start; base < end; base += 64) {
        int i = base + lane;
        int cnt = min(64, end - base);
        int s = 0;
        float p = 0.f;
        if (i < end) {
            s = csr[i];
            float t = asb[s] + ad;
            float e = (t > 0.f) ? t : NEG_SLOPE * t;
            p = __expf(e - m);
        }
        dsum += p;
        for (int j = 0; j < cnt; j++) {
            float pj = __shfl(p, j, 64);
            int sj = __shfl(s, j, 64);
            acc = fmaf(pj, (float)H[(size_t)sj * FP + lf], acc);
        }
    }
    for (int o = 32; o > 0; o >>= 1) dsum += __shfl_xor(dsum, o, 64);

    float b = (lf < Freal) ? bias[lf] : 0.f;
    float z = acc / dsum + b;
    if (mode == 0) {
        if (lane < FP) out[(size_t)node * FP + lane] = fmaxf(z, 0.f);
    } else {
        float zz = (lane < Freal) ? z : NEG_INF;
        float zm = zz;
        for (int o = 32; o > 0; o >>= 1) zm = fmaxf(zm, __shfl_xor(zm, o, 64));
        float ez = (lane < Freal) ? __expf(zz - zm) : 0.f;
        float es = ez;
        for (int o = 32; o > 0; o >>= 1) es += __shfl_xor(es, o, 64);
        if (lane < Freal) out[(size_t)node * Freal + lane] = zz - zm - __logf(es);
    }
}

// ---------------- Aggregation: dual-node wave, vector gather ---------------
// Half h of the wave owns node 2*wid+h (deg<=32 fast path). Scores + max/
// dsum butterflies within the 32-lane half (offsets 16..1). Gather: LPR
// lanes/row, GRPH=32/LPR rows in flight per half, W halfs (2W bytes)/lane.
// Loop bound degm = max(degA,degB) is wave-uniform; shuffle index
// half*32+jb+g <= half*32+31 stays in-half; overshoot lanes get p=0,s=0.
template <int FP, int W>
__global__ __launch_bounds__(256) void k_agg(
    const _Float16* __restrict__ H, const float* __restrict__ asb,
    const float* __restrict__ adb, const float* __restrict__ bias,
    const int* __restrict__ rowptr, const int* __restrict__ csr,
    int N, int Freal, float* __restrict__ out, int mode) {
    constexpr int LPR = FP / W;    // lanes per row (within a half)
    constexpr int GRPH = 32 / LPR; // rows in flight per half
    using vecW = typename std::conditional<W == 8, h8v, h4v>::type;
    int lane = threadIdx.x & 63;
    int half = lane >> 5;
    int li = lane & 31;
    int wid = (blockIdx.x * blockDim.x + threadIdx.x) >> 6;
    int nA = 2 * wid;
    if (nA >= N) return;
    int n = nA + half;
    bool valid = (n < N);
    int start = 0, end = 0;
    float ad = 0.f;
    if (valid) {
        start = rowptr[n];
        end = rowptr[n + 1];
        ad = adb[n];
    }
    int deg = end - start;
    int degm = max(deg, __shfl_xor(deg, 32, 64));  // wave-uniform

    const float NEG_INF = -__builtin_inff();

    if (degm <= 32) {
        int g = li / LPR;   // row-group within half
        int fl = li % LPR;  // vecW slot within row
        int s = 0;
        float e = NEG_INF;
        if (li < deg) {
            s = csr[start + li];
            float t = asb[s] + ad;
            e = (t > 0.f) ? t : NEG_SLOPE * t;
        }
        float m = e;
        for (int o = 16; o > 0; o >>= 1) m = fmaxf(m, __shfl_xor(m, o, 64));
        float p = (li < deg) ? __expf(e - m) : 0.f;
        float dsum = p;
        for (int o = 16; o > 0; o >>= 1) dsum += __shfl_xor(dsum, o, 64);

        float acc[W];
#pragma unroll
        for (int c = 0; c < W; c++) acc[c] = 0.f;
#pragma unroll 2
        for (int jb = 0; jb < degm; jb += GRPH) {  // wave-uniform bound
            int gidx = half * 32 + jb + g;         // in-half, <= half*32+31
            float pj = __shfl(p, gidx, 64);        // 0 for jb+g >= deg
            int sj = __shfl(s, gidx, 64);          // 0 for jb+g >= deg
            vecW r = ((const vecW*)(H + (size_t)sj * FP))[fl];
#pragma unroll
            for (int c = 0; c < W; c++) acc[c] = fmaf(pj, (float)r[c], acc[c]);
        }
        // cross-group butterfly within half: offsets LPR..16 preserve fl
        for (int o = LPR; o < 32; o <<= 1) {
#pragma unroll
            for (int c = 0; c < W; c++) acc[c] += __shfl_xor(acc[c], o, 64);
        }
        float inv = 1.f / dsum;
        int fbase = fl * W;

        if (mode == 0) {
            if (valid && li < LPR) {
                float z[W];
#pragma unroll
                for (int c = 0; c < W; c++)
                    z[c] = fmaxf(fmaf(acc[c], inv, bias[fbase + c]), 0.f);
                float4* op = (float4*)(out + (size_t)n * FP + fbase);
#pragma unroll
                for (int q = 0; q < W / 4; q++)
                    op[q] = make_float4(z[4 * q], z[4 * q + 1], z[4 * q + 2],
                                        z[4 * q + 3]);
            }
        } else {
            float zc[W];
#pragma unroll
            for (int c = 0; c < W; c++) {
                int f = fbase + c;
                zc[c] = (f < Freal) ? fmaf(acc[c], inv, bias[f]) : NEG_INF;
            }
            float vm = zc[0];
#pragma unroll
            for (int c = 1; c < W; c++) vm = fmaxf(vm, zc[c]);
            for (int o = 1; o < LPR; o <<= 1) vm = fmaxf(vm, __shfl_xor(vm, o, 64));
            float es = 0.f;
#pragma unroll
            for (int c = 0; c < W; c++) es += __expf(zc[c] - vm);
            for (int o = 1; o < LPR; o <<= 1) es += __shfl_xor(es, o, 64);
            float ls = __logf(es);
            if (valid && li < LPR) {
#pragma unroll
                for (int c = 0; c < W; c++) {
                    int f = fbase + c;
                    if (f < Freal) out[(size_t)n * Freal + f] = zc[c] - vm - ls;
                }
            }
        }
    } else {
        // rare (P(deg>32) ~ 2e-4): whole-wave per node, R4-proven path
        agg_slow<FP>(nA, H, asb, adb, bias, rowptr, csr, N, Freal, out, mode, lane);
        agg_slow<FP>(nA + 1, H, asb, adb, bias, rowptr, csr, N, Freal, out, mode, lane);
    }
}

// ---------------------------------------------------------------------------
extern "C" void kernel_launch(void* const* d_in, const int* in_sizes, int n_in,
                              void* d_out, int out_size, void* d_ws, size_t ws_size,
                              hipStream_t stream) {
    const float* x = (const float*)d_in[0];
    const int* ei = (const int*)d_in[1];
    const float* W1 = (const float*)d_in[2];
    const float* a1s = (const float*)d_in[3];
    const float* a1d = (const float*)d_in[4];
    const float* b1 = (const float*)d_in[5];
    const float* W2 = (const float*)d_in[6];
    const float* a2s = (const float*)d_in[7];
    const float* a2d = (const float*)d_in[8];
    const float* b2 = (const float*)d_in[9];
    const float* W3 = (const float*)d_in[10];
    const float* a3s = (const float*)d_in[11];
    const float* a3d = (const float*)d_in[12];
    const float* b3 = (const float*)d_in[13];

    const int N = in_sizes[0] / 64;
    const int E = in_sizes[1] / 2;
    const int Etot = E + N;
    const int nb = (N + BKT_SZ - 1) >> BKT_BITS;  // buckets of 512 nodes
    const int* srcv = ei;
    const int* dstv = ei + E;

    // workspace carve (256B aligned)
    size_t off = 0;
    char* base = (char*)d_ws;
    auto carve = [&](size_t bytes) -> void* {
        void* p = base + off;
        off = (off + bytes + 255) & ~(size_t)255;
        return p;
    };
    int* bcount = (int*)carve((size_t)(nb + 1) * 4);
    int* ebase = (int*)carve((size_t)(nb + 1) * 4);
    int* gcur = (int*)carve((size_t)nb * 4);
    int* rowptr = (int*)carve((size_t)(N + 1) * 4);
    int* csr = (int*)carve((size_t)Etot * 4);
    float* asb = (float*)carve((size_t)N * 4);
    float* adb = (float*)carve((size_t)N * 4);
    _Float16* hA = (_Float16*)carve((size_t)N * 64 * 2);  // fp16 H (layers 1,2)
    float* fB = (float*)carve((size_t)N * 64 * 4);        // fp32 agg out / X
    _Float16* hC = (_Float16*)carve((size_t)N * 16 * 2);  // fp16 H (layer 3)
    int* ebuf = (int*)hA;  // alias: ebuf (E*4 <= N*64*2) only live pre-layer-1

    // ---- CSR build (bucket sort) ----
    k_zero<<<(nb + 255) / 256, 256, 0, stream>>>(bcount, nb);
    k_hist<<<512, 256, 0, stream>>>(dstv, E, nb, bcount);
    k_bscan<<<1, BKT_SZ, 0, stream>>>(bcount, nb, E, N, ebase, gcur, rowptr);
    k_bscatter<<<(E + 8191) / 8192, 1024, 0, stream>>>(srcv, dstv, E, nb, gcur, ebuf);
    k_bcsr<<<nb, BKT_SZ, 0, stream>>>(ebuf, ebase, N, rowptr, csr);

    const int aggBlocks = (N + 7) / 8;  // 4 waves/block, 2 nodes/wave

    // ---- layer 1 ----
    k_gemm<64><<<1024, 256, 0, stream>>>(x, W1, a1s, a1d, N, 64, hA, asb, adb);
    k_agg<64, 8><<<aggBlocks, 256, 0, stream>>>(hA, asb, adb, b1, rowptr, csr, N, 64, fB, 0);
    // ---- layer 2 ----
    k_gemm<64><<<1024, 256, 0, stream>>>(fB, W2, a2s, a2d, N, 64, hA, asb, adb);
    k_agg<64, 8><<<aggBlocks, 256, 0, stream>>>(hA, asb, adb, b2, rowptr, csr, N, 64, fB, 0);
    // ---- layer 3 ----
    k_gemm<16><<<1024, 256, 0, stream>>>(fB, W3, a3s, a3d, N, 10, hC, asb, adb);
    k_agg<16, 4><<<aggBlocks, 256, 0, stream>>>(hC, asb, adb, b3, rowptr, csr, N, 10,
                                                (float*)d_out, 1);
}